// Round 7
// baseline (232.512 us; speedup 1.0000x reference)
//
#include <hip/hip_runtime.h>
#include <math.h>

#define DIMC 512
#define NG 8
// q pre-scale: 64^-0.5 * log2(e)  (so scores come out in exp2 units)
#define QSCALE 0.18033688011112042f
// softmax fixed shift: 5 * log2(e)
#define MSHIFT 7.2134752044448170f

typedef _Float16 half8 __attribute__((ext_vector_type(8)));
typedef __fp16 fp16x2 __attribute__((ext_vector_type(2)));
typedef float f32x4 __attribute__((ext_vector_type(4)));

// ---------------- Wo f32 -> f16 cast (native [d][c] layout == MFMA B layout) ----------------
__global__ __launch_bounds__(256) void k_wcvt(const float* __restrict__ Wo, _Float16* __restrict__ Woh) {
    int idx = (blockIdx.x*256 + threadIdx.x) * 8;
    float4 a = *(const float4*)&Wo[idx];
    float4 b = *(const float4*)&Wo[idx+4];
    union { _Float16 h[8]; uint4 v; } pk;
    pk.h[0]=(_Float16)a.x; pk.h[1]=(_Float16)a.y; pk.h[2]=(_Float16)a.z; pk.h[3]=(_Float16)a.w;
    pk.h[4]=(_Float16)b.x; pk.h[5]=(_Float16)b.y; pk.h[6]=(_Float16)b.z; pk.h[7]=(_Float16)b.w;
    *(uint4*)&Woh[idx] = pk.v;
}

// ---------------- q = grouped 1x1 conv over concat[prev_x, x] ----------------
__global__ __launch_bounds__(256) void k_qconv(
    const float* __restrict__ x, const float* __restrict__ px,
    const float* __restrict__ Wq, float* __restrict__ q, _Float16* __restrict__ qh, int n)
{
    __shared__ float Xs[64][129];
    __shared__ float Wt[128][68];
    int g  = blockIdx.x;            // 0..7 == head
    int i0 = blockIdx.y * 64;
    int t  = threadIdx.x;
    const float* SRC = (g < 4) ? px : x;   // concat puts prev first
    int cbase = (g & 3) * 128;
#pragma unroll
    for (int r = 0; r < 8; ++r) {
        int f = t + 256*r;
        int i = f >> 5, kq = f & 31;
        float4 v = *(const float4*)&SRC[(size_t)(i0+i)*DIMC + cbase + kq*4];
        Xs[i][kq*4+0] = v.x; Xs[i][kq*4+1] = v.y; Xs[i][kq*4+2] = v.z; Xs[i][kq*4+3] = v.w;
    }
#pragma unroll
    for (int r = 0; r < 32; ++r) {
        int f = t + 256*r;
        int oc = f & 63, kk = f >> 6;
        Wt[kk][oc] = Wq[(size_t)(g*64+oc)*128 + kk];
    }
    __syncthreads();
    int lane = t & 63, w = t >> 6;         // lane = i, wave owns 16 oc
    float acc[16];
#pragma unroll
    for (int u = 0; u < 16; ++u) acc[u] = 0.f;
#pragma unroll 4
    for (int k = 0; k < 128; ++k) {
        float xv = Xs[lane][k];
#pragma unroll
        for (int q4 = 0; q4 < 4; ++q4) {
            float4 wv = *(const float4*)&Wt[k][w*16 + q4*4];   // broadcast
            acc[q4*4+0] += xv*wv.x; acc[q4*4+1] += xv*wv.y;
            acc[q4*4+2] += xv*wv.z; acc[q4*4+3] += xv*wv.w;
        }
    }
#pragma unroll
    for (int u = 0; u < 16; ++u)           // coalesced over lane=i
        q[(size_t)(g*64 + w*16 + u)*n + i0 + lane] = acc[u];
    // transpose through LDS -> qh f16 [h][i][d], scaled by QSCALE
    __syncthreads();
#pragma unroll
    for (int u = 0; u < 16; ++u) Xs[lane][w*16 + u] = acc[u];
    __syncthreads();
    {
        int i = t >> 2, qd = t & 3;
        union { _Float16 h[16]; uint4 v[2]; } pk;
#pragma unroll
        for (int v = 0; v < 16; ++v) pk.h[v] = (_Float16)(Xs[i][qd*16 + v] * QSCALE);
        uint4* dst = (uint4*)&qh[((size_t)g*n + i0 + i)*64 + qd*16];
        dst[0] = pk.v[0]; dst[1] = pk.v[1];
    }
}

// ---------------- offset net ----------------
#define SW 136
__global__ __launch_bounds__(256) void k_off(
    const float* __restrict__ q, const float* __restrict__ Wdw,
    const float* __restrict__ bdw, const float* __restrict__ Wp,
    int* __restrict__ x0i, float* __restrict__ w1f, int n, int m)
{
    __shared__ float qs[64][SW];
    __shared__ float part[8][36];
    int g  = blockIdx.x & 7;
    int j0 = (blockIdx.x >> 3) * 32;
    int t  = threadIdx.x;
    int lane = t & 63, wv = t >> 6;
    int pbase = 4*j0 - 1;
#pragma unroll
    for (int rr = 0; rr < 16; ++rr) {
        int row = rr*4 + wv;
        const float* src = &q[(size_t)(g*64 + row)*n];
#pragma unroll
        for (int cc = 0; cc < 3; ++cc) {
            int col = cc*64 + lane;
            if (col < SW) {
                int p = pbase + col;
                qs[row][col] = (p >= 0 && p < n) ? src[p] : 0.f;
            }
        }
    }
    __syncthreads();
    int j  = t & 31, cg = t >> 5;
    float acc = 0.f;
#pragma unroll
    for (int cc = 0; cc < 8; ++cc) {
        int c = cg*8 + cc;
        float h = bdw[c];
#pragma unroll
        for (int tt = 0; tt < 6; ++tt)
            h += Wdw[c*6 + tt] * qs[c][4*j + tt];
        float ge = 0.5f * h * (1.0f + erff(h * 0.70710678118654752f));  // exact gelu
        acc += Wp[c] * ge;
    }
    part[cg][j] = acc;
    __syncthreads();
    if (t < 32) {
        float off = 0.f;
#pragma unroll
        for (int cg2 = 0; cg2 < 8; ++cg2) off += part[cg2][t];
        off = tanhf(off) * 4.0f;
        int jg = j0 + t;
        float vg  = 2.0f * ((float)jg + off) / (float)(m - 1) - 1.0f;
        float pos = ((vg + 1.0f) * (float)n - 1.0f) * 0.5f;
        float x0  = floorf(pos);
        x0i[g*m + jg] = (int)x0;
        w1f[g*m + jg] = pos - x0;
    }
}

// ---------------- grid-sample + k/v grouped 1x1 convs ----------------
__global__ __launch_bounds__(256) void k_kv(
    const float* __restrict__ x, const float* __restrict__ px,
    const float* __restrict__ Wk, const float* __restrict__ Wv,
    const int* __restrict__ x0i, const float* __restrict__ w1f,
    _Float16* __restrict__ kt16, _Float16* __restrict__ vt16, int n, int m)
{
    __shared__ float Wks[64][65];
    __shared__ float Wvs[64][65];
    __shared__ float kvs[4][64];
    __shared__ int   x0s[64];
    __shared__ float w1s[64];
    int nj = m >> 6;
    int jc = blockIdx.x % nj;
    int g  = (blockIdx.x / nj) & 7;
    int s  = blockIdx.x / (nj*8);
    int t  = threadIdx.x;
    int j0 = jc*64;
#pragma unroll
    for (int r = 0; r < 16; ++r) {
        int f = t + 256*r;
        int oc = f >> 6, ic = f & 63;
        Wks[oc][ic] = Wk[(size_t)(g*64+oc)*64 + ic];
        Wvs[oc][ic] = Wv[(size_t)(g*64+oc)*64 + ic];
    }
    if (t < 64) { x0s[t] = x0i[g*m + j0 + t]; w1s[t] = w1f[g*m + j0 + t]; }
    __syncthreads();
    const float* SRC = s ? x : px;
    int jl = t >> 6, c = t & 63;
    for (int jq = 0; jq < 16; ++jq) {
        int jloc = jq*4 + jl;
        int i0 = x0s[jloc];
        float wgt = w1s[jloc];
        float v0 = (i0 >= 0   && i0   < n) ? SRC[(size_t)i0*DIMC + g*64 + c]     : 0.f;
        float v1 = (i0+1 >= 0 && i0+1 < n) ? SRC[(size_t)(i0+1)*DIMC + g*64 + c] : 0.f;
        kvs[jl][c] = v0*(1.0f - wgt) + v1*wgt;
        __syncthreads();
        float ka = 0.f, va = 0.f;
#pragma unroll 8
        for (int ic = 0; ic < 64; ++ic) {
            float kvv = kvs[jl][ic];
            ka += Wks[c][ic]*kvv;
            va += Wvs[c][ic]*kvv;
        }
        kt16[((size_t)(s*8+g)*m + j0 + jloc)*64 + c]   = (_Float16)ka;
        vt16[((size_t)(s*8+g)*64 + c)*m + j0 + jloc]   = (_Float16)va;
        __syncthreads();
    }
}

// ---------------- flash attention v3: barrier-free K-loop, direct global->reg fragments ----------------
// Block = (s,h, 128-query tile); wave w owns i in [w*32, w*32+32). No LDS in the K-loop.
// QK: A = K frags (global), B = Q frags (global, hoisted) -> S^T C-layout
// PV: A = V^T frags (global), B = P^T built in-register via shuffles -> O^T C-layout
__global__ __launch_bounds__(256, 2) void k_attn(
    const _Float16* __restrict__ qh, const _Float16* __restrict__ kt16,
    const _Float16* __restrict__ vt16, _Float16* __restrict__ aoh, int n, int m)
{
    __shared__ _Float16 Os[128*72];  // epilogue transpose only (wave-private strips)
    int nit = n >> 7;
    int it = blockIdx.x % nit;
    int h  = (blockIdx.x / nit) & 7;
    int s  = blockIdx.x / (nit*8);
    int t  = threadIdx.x;
    int lane = t & 63, w = t >> 6;
    int l15 = lane & 15, quad = lane >> 4;
    int i0 = it*128;

    // Q B-frags: load once, keep in registers
    const _Float16* qb = &qh[((size_t)h*n + i0)*64];
    half8 bqv[2][2];
#pragma unroll
    for (int ks = 0; ks < 2; ++ks)
#pragma unroll
        for (int i2 = 0; i2 < 2; ++i2)
            bqv[ks][i2] = *(const half8*)&qb[(w*32 + i2*16 + l15)*64 + ks*32 + quad*8];

    // per-lane fragment base pointers
    const _Float16* kl = &kt16[(size_t)(s*8+h)*m*64 + l15*64 + quad*8];      // + tk*4096 + jt*1024 + ks*32
    const _Float16* vl = &vt16[(size_t)(s*8+h)*64*m + (size_t)l15*m + quad*8]; // + dt*16*m + tk*64 + ks*32

    float lsum[2] = {0.f, 0.f};
    f32x4 oaccT[4][2];
#pragma unroll
    for (int dt = 0; dt < 4; ++dt)
#pragma unroll
        for (int i2 = 0; i2 < 2; ++i2) oaccT[dt][i2] = (f32x4){0.f,0.f,0.f,0.f};

    int ntile = m >> 6;
    for (int tk = 0; tk < ntile; ++tk) {
        // --- direct global->reg fragment loads (issue all early; no barriers) ---
        half8 aqv[2][4];   // K frags [ks][jt]
        half8 avv[2][4];   // V^T frags [ks][dt]
#pragma unroll
        for (int ks = 0; ks < 2; ++ks)
#pragma unroll
            for (int jt = 0; jt < 4; ++jt)
                aqv[ks][jt] = *(const half8*)&kl[tk*4096 + jt*1024 + ks*32];
#pragma unroll
        for (int ks = 0; ks < 2; ++ks)
#pragma unroll
            for (int dt = 0; dt < 4; ++dt)
                avv[ks][dt] = *(const half8*)&vl[(size_t)dt*16*m + tk*64 + ks*32];

        // --- S^T = K Q^T over wave's 32-i strip ---
        f32x4 accs[4][2];
#pragma unroll
        for (int jt = 0; jt < 4; ++jt)
#pragma unroll
            for (int i2 = 0; i2 < 2; ++i2) accs[jt][i2] = (f32x4){0.f,0.f,0.f,0.f};
#pragma unroll
        for (int ks = 0; ks < 2; ++ks)
#pragma unroll
            for (int jt = 0; jt < 4; ++jt)
#pragma unroll
                for (int i2 = 0; i2 < 2; ++i2)
                    accs[jt][i2] = __builtin_amdgcn_mfma_f32_16x16x32_f16(
                        aqv[ks][jt], bqv[ks][i2], accs[jt][i2], 0, 0, 0);

        // --- p = exp2(t - MSHIFT); per-lane partial row sums; pack f16 ---
        int pki[4][2][2];
#pragma unroll
        for (int jt = 0; jt < 4; ++jt)
#pragma unroll
            for (int i2 = 0; i2 < 2; ++i2) {
                f32x4 p;
#pragma unroll
                for (int r = 0; r < 4; ++r) p[r] = __builtin_amdgcn_exp2f(accs[jt][i2][r] - MSHIFT);
                lsum[i2] += (p[0]+p[1]) + (p[2]+p[3]);
                union { fp16x2 h; int i; } c0, c1;
                c0.h = __builtin_amdgcn_cvt_pkrtz(p[0], p[1]);
                c1.h = __builtin_amdgcn_cvt_pkrtz(p[2], p[3]);
                pki[jt][i2][0] = c0.i;
                pki[jt][i2][1] = c1.i;
            }

        // --- O^T += V^T P^T : build P^T B-frags via shuffles ---
        int qsel = quad >> 1;
        int qlow = (quad & 1) * 32;
#pragma unroll
        for (int ks = 0; ks < 2; ++ks)
#pragma unroll
            for (int i2 = 0; i2 < 2; ++i2) {
                union { half8 h; int i4[4]; } bp;
#pragma unroll
                for (int pp = 0; pp < 4; ++pp) {
                    int srcLane = qlow + (pp >> 1)*16 + l15;
                    int v0 = __shfl(pki[2*ks  ][i2][pp & 1], srcLane, 64);
                    int v1 = __shfl(pki[2*ks+1][i2][pp & 1], srcLane, 64);
                    bp.i4[pp] = qsel ? v1 : v0;
                }
#pragma unroll
                for (int dt = 0; dt < 4; ++dt)
                    oaccT[dt][i2] = __builtin_amdgcn_mfma_f32_16x16x32_f16(
                        avv[ks][dt], bp.h, oaccT[dt][i2], 0, 0, 0);
            }
    }

    // --- finalize: reduce l across quads, normalize, transpose via Os, store ---
#pragma unroll
    for (int i2 = 0; i2 < 2; ++i2) {
        lsum[i2] += __shfl_xor(lsum[i2], 16, 64);
        lsum[i2] += __shfl_xor(lsum[i2], 32, 64);
    }
    float inv[2] = {1.0f / lsum[0], 1.0f / lsum[1]};
    // wave-private strip of Os: rows w*32 .. w*32+31 — no barrier needed
#pragma unroll
    for (int dt = 0; dt < 4; ++dt)
#pragma unroll
        for (int i2 = 0; i2 < 2; ++i2)
#pragma unroll
            for (int r = 0; r < 4; ++r)
                Os[(w*32 + i2*16 + l15)*72 + dt*16 + quad*4 + r]
                    = (_Float16)(oaccT[dt][i2][r] * inv[i2]);
    {
        int row = w*32 + (lane >> 1);
        int dbase = (lane & 1) * 32;
        size_t gbase = (size_t)(i0 + row)*1024 + s*512 + h*64 + dbase;
#pragma unroll
        for (int k2 = 0; k2 < 4; ++k2) {
            uint4 v = *(uint4*)&Os[row*72 + dbase + k2*8];
            *(uint4*)&aoh[gbase + k2*8] = v;
        }
    }
}

// ---------------- Wo GEMM, f16 MFMA ----------------
__global__ __launch_bounds__(256) void k_out(
    const _Float16* __restrict__ aoh, const _Float16* __restrict__ Woh,
    const float* __restrict__ bo, float* __restrict__ out, int n)
{
    __shared__ _Float16 As[64*72];   // [i][k]
    __shared__ _Float16 Ws[64*72];   // [d][k]
    int i0 = blockIdx.x*64, d0 = blockIdx.y*64;
    int t = threadIdx.x;
    int lane = t & 63, w = t >> 6;
    int l15 = lane & 15, quad = lane >> 4;
    f32x4 oacc[4];
#pragma unroll
    for (int dt = 0; dt < 4; ++dt) oacc[dt] = (f32x4){0.f,0.f,0.f,0.f};

    for (int kc = 0; kc < 16; ++kc) {
        int cbase = (kc & 7) * 64;
        __syncthreads();
#pragma unroll
        for (int r = 0; r < 2; ++r) {
            int c = t + 256*r;
            int row = c >> 3, oct = c & 7;
            *(uint4*)&As[row*72 + oct*8] = *(const uint4*)&aoh[(size_t)(i0+row)*1024 + kc*64 + oct*8];
            *(uint4*)&Ws[row*72 + oct*8] = *(const uint4*)&Woh[(size_t)(d0+row)*DIMC + cbase + oct*8];
        }
        __syncthreads();
#pragma unroll
        for (int ks = 0; ks < 2; ++ks) {
            half8 aq = *(const half8*)&As[(w*16 + l15)*72 + ks*32 + quad*8];
#pragma unroll
            for (int dt = 0; dt < 4; ++dt) {
                half8 bw = *(const half8*)&Ws[(dt*16 + l15)*72 + ks*32 + quad*8];
                oacc[dt] = __builtin_amdgcn_mfma_f32_16x16x32_f16(aq, bw, oacc[dt], 0, 0, 0);
            }
        }
    }
#pragma unroll
    for (int dt = 0; dt < 4; ++dt) {
        float bias = bo[d0 + dt*16 + l15];
#pragma unroll
        for (int r = 0; r < 4; ++r)
            out[(size_t)(i0 + w*16 + quad*4 + r)*DIMC + d0 + dt*16 + l15]
                = bias + 0.5f*oacc[dt][r];
    }
}

extern "C" void kernel_launch(void* const* d_in, const int* in_sizes, int n_in,
                              void* d_out, int out_size, void* d_ws, size_t ws_size,
                              hipStream_t stream)
{
    const float* x   = (const float*)d_in[0];
    const float* px  = (const float*)d_in[1];
    const float* Wq  = (const float*)d_in[2];
    const float* Wk  = (const float*)d_in[3];
    const float* Wv  = (const float*)d_in[4];
    const float* Wo  = (const float*)d_in[5];
    const float* bo  = (const float*)d_in[6];
    const float* Wdw = (const float*)d_in[7];
    const float* bdw = (const float*)d_in[8];
    const float* Wp  = (const float*)d_in[9];
    float* out = (float*)d_out;
    int n = in_sizes[0] / DIMC;     // 4096
    int m = n / 4;                  // 1024

    float* ws  = (float*)d_ws;
    float* q    = ws;                                 // 512*n f32
    int*   x0i  = (int*)(q + (size_t)512*n);          // 8*m
    float* w1f  = (float*)(x0i + 8*m);                // 8*m
    _Float16* qhf  = (_Float16*)(w1f + 8*m);          // 8*n*64 f16   [h][i][d]
    _Float16* kt16 = qhf + (size_t)8*n*64;            // 2*8*m*64 f16 [s][h][j][d]
    _Float16* vt16 = kt16 + (size_t)16*m*64;          // 2*8*m*64 f16 [s][h][d][j]
    _Float16* aoh  = vt16 + (size_t)16*m*64;          // n*1024 f16   [i][c']
    _Float16* Woh  = aoh + (size_t)n*1024;            // 512*512 f16  [d][c]

    k_wcvt <<<128,              256, 0, stream>>>(Wo, Woh);
    k_qconv<<<dim3(8, n/64),    256, 0, stream>>>(x, px, Wq, q, qhf, n);
    k_off  <<<8*(m/32),         256, 0, stream>>>(q, Wdw, bdw, Wp, x0i, w1f, n, m);
    k_kv   <<<2*8*(m/64),       256, 0, stream>>>(x, px, Wk, Wv, x0i, w1f, kt16, vt16, n, m);
    k_attn <<<2*8*(n/128),      256, 0, stream>>>(qhf, kt16, vt16, aoh, n, m);
    k_out  <<<dim3(n/64, 8),    256, 0, stream>>>(aoh, Woh, bo, out, n);
}

// Round 8
// 195.679 us; speedup vs baseline: 1.1882x; 1.1882x over previous
//
#include <hip/hip_runtime.h>
#include <math.h>

#define DIMC 512
#define NG 8
// q pre-scale: 64^-0.5 * log2(e)  (so scores come out in exp2 units)
#define QSCALE 0.18033688011112042f
// softmax fixed shift: 5 * log2(e)
#define MSHIFT 7.2134752044448170f

typedef _Float16 half8 __attribute__((ext_vector_type(8)));
typedef __fp16 fp16x2 __attribute__((ext_vector_type(2)));
typedef float f32x4 __attribute__((ext_vector_type(4)));

// ---------------- Wo f32 -> f16 cast (native [d][c] layout == MFMA B layout) ----------------
__global__ __launch_bounds__(256) void k_wcvt(const float* __restrict__ Wo, _Float16* __restrict__ Woh) {
    int idx = (blockIdx.x*256 + threadIdx.x) * 8;
    float4 a = *(const float4*)&Wo[idx];
    float4 b = *(const float4*)&Wo[idx+4];
    union { _Float16 h[8]; uint4 v; } pk;
    pk.h[0]=(_Float16)a.x; pk.h[1]=(_Float16)a.y; pk.h[2]=(_Float16)a.z; pk.h[3]=(_Float16)a.w;
    pk.h[4]=(_Float16)b.x; pk.h[5]=(_Float16)b.y; pk.h[6]=(_Float16)b.z; pk.h[7]=(_Float16)b.w;
    *(uint4*)&Woh[idx] = pk.v;
}

// ---------------- q = grouped 1x1 conv over concat[prev_x, x] ----------------
__global__ __launch_bounds__(256) void k_qconv(
    const float* __restrict__ x, const float* __restrict__ px,
    const float* __restrict__ Wq, float* __restrict__ q, _Float16* __restrict__ qh, int n)
{
    __shared__ float Xs[64][129];
    __shared__ float Wt[128][68];
    int g  = blockIdx.x;            // 0..7 == head
    int i0 = blockIdx.y * 64;
    int t  = threadIdx.x;
    const float* SRC = (g < 4) ? px : x;   // concat puts prev first
    int cbase = (g & 3) * 128;
#pragma unroll
    for (int r = 0; r < 8; ++r) {
        int f = t + 256*r;
        int i = f >> 5, kq = f & 31;
        float4 v = *(const float4*)&SRC[(size_t)(i0+i)*DIMC + cbase + kq*4];
        Xs[i][kq*4+0] = v.x; Xs[i][kq*4+1] = v.y; Xs[i][kq*4+2] = v.z; Xs[i][kq*4+3] = v.w;
    }
#pragma unroll
    for (int r = 0; r < 32; ++r) {
        int f = t + 256*r;
        int oc = f & 63, kk = f >> 6;
        Wt[kk][oc] = Wq[(size_t)(g*64+oc)*128 + kk];
    }
    __syncthreads();
    int lane = t & 63, w = t >> 6;         // lane = i, wave owns 16 oc
    float acc[16];
#pragma unroll
    for (int u = 0; u < 16; ++u) acc[u] = 0.f;
#pragma unroll 4
    for (int k = 0; k < 128; ++k) {
        float xv = Xs[lane][k];
#pragma unroll
        for (int q4 = 0; q4 < 4; ++q4) {
            float4 wv = *(const float4*)&Wt[k][w*16 + q4*4];   // broadcast
            acc[q4*4+0] += xv*wv.x; acc[q4*4+1] += xv*wv.y;
            acc[q4*4+2] += xv*wv.z; acc[q4*4+3] += xv*wv.w;
        }
    }
#pragma unroll
    for (int u = 0; u < 16; ++u)           // coalesced over lane=i
        q[(size_t)(g*64 + w*16 + u)*n + i0 + lane] = acc[u];
    // transpose through LDS -> qh f16 [h][i][d], scaled by QSCALE
    __syncthreads();
#pragma unroll
    for (int u = 0; u < 16; ++u) Xs[lane][w*16 + u] = acc[u];
    __syncthreads();
    {
        int i = t >> 2, qd = t & 3;
        union { _Float16 h[16]; uint4 v[2]; } pk;
#pragma unroll
        for (int v = 0; v < 16; ++v) pk.h[v] = (_Float16)(Xs[i][qd*16 + v] * QSCALE);
        uint4* dst = (uint4*)&qh[((size_t)g*n + i0 + i)*64 + qd*16];
        dst[0] = pk.v[0]; dst[1] = pk.v[1];
    }
}

// ---------------- offset net ----------------
#define SW 136
__global__ __launch_bounds__(256) void k_off(
    const float* __restrict__ q, const float* __restrict__ Wdw,
    const float* __restrict__ bdw, const float* __restrict__ Wp,
    int* __restrict__ x0i, float* __restrict__ w1f, int n, int m)
{
    __shared__ float qs[64][SW];
    __shared__ float part[8][36];
    int g  = blockIdx.x & 7;
    int j0 = (blockIdx.x >> 3) * 32;
    int t  = threadIdx.x;
    int lane = t & 63, wv = t >> 6;
    int pbase = 4*j0 - 1;
#pragma unroll
    for (int rr = 0; rr < 16; ++rr) {
        int row = rr*4 + wv;
        const float* src = &q[(size_t)(g*64 + row)*n];
#pragma unroll
        for (int cc = 0; cc < 3; ++cc) {
            int col = cc*64 + lane;
            if (col < SW) {
                int p = pbase + col;
                qs[row][col] = (p >= 0 && p < n) ? src[p] : 0.f;
            }
        }
    }
    __syncthreads();
    int j  = t & 31, cg = t >> 5;
    float acc = 0.f;
#pragma unroll
    for (int cc = 0; cc < 8; ++cc) {
        int c = cg*8 + cc;
        float h = bdw[c];
#pragma unroll
        for (int tt = 0; tt < 6; ++tt)
            h += Wdw[c*6 + tt] * qs[c][4*j + tt];
        float ge = 0.5f * h * (1.0f + erff(h * 0.70710678118654752f));  // exact gelu
        acc += Wp[c] * ge;
    }
    part[cg][j] = acc;
    __syncthreads();
    if (t < 32) {
        float off = 0.f;
#pragma unroll
        for (int cg2 = 0; cg2 < 8; ++cg2) off += part[cg2][t];
        off = tanhf(off) * 4.0f;
        int jg = j0 + t;
        float vg  = 2.0f * ((float)jg + off) / (float)(m - 1) - 1.0f;
        float pos = ((vg + 1.0f) * (float)n - 1.0f) * 0.5f;
        float x0  = floorf(pos);
        x0i[g*m + jg] = (int)x0;
        w1f[g*m + jg] = pos - x0;
    }
}

// ---------------- grid-sample + k/v grouped 1x1 convs ----------------
__global__ __launch_bounds__(256) void k_kv(
    const float* __restrict__ x, const float* __restrict__ px,
    const float* __restrict__ Wk, const float* __restrict__ Wv,
    const int* __restrict__ x0i, const float* __restrict__ w1f,
    _Float16* __restrict__ kt16, _Float16* __restrict__ vt16, int n, int m)
{
    __shared__ float Wks[64][65];
    __shared__ float Wvs[64][65];
    __shared__ float kvs[4][64];
    __shared__ int   x0s[64];
    __shared__ float w1s[64];
    int nj = m >> 6;
    int jc = blockIdx.x % nj;
    int g  = (blockIdx.x / nj) & 7;
    int s  = blockIdx.x / (nj*8);
    int t  = threadIdx.x;
    int j0 = jc*64;
#pragma unroll
    for (int r = 0; r < 16; ++r) {
        int f = t + 256*r;
        int oc = f >> 6, ic = f & 63;
        Wks[oc][ic] = Wk[(size_t)(g*64+oc)*64 + ic];
        Wvs[oc][ic] = Wv[(size_t)(g*64+oc)*64 + ic];
    }
    if (t < 64) { x0s[t] = x0i[g*m + j0 + t]; w1s[t] = w1f[g*m + j0 + t]; }
    __syncthreads();
    const float* SRC = s ? x : px;
    int jl = t >> 6, c = t & 63;
    for (int jq = 0; jq < 16; ++jq) {
        int jloc = jq*4 + jl;
        int i0 = x0s[jloc];
        float wgt = w1s[jloc];
        float v0 = (i0 >= 0   && i0   < n) ? SRC[(size_t)i0*DIMC + g*64 + c]     : 0.f;
        float v1 = (i0+1 >= 0 && i0+1 < n) ? SRC[(size_t)(i0+1)*DIMC + g*64 + c] : 0.f;
        kvs[jl][c] = v0*(1.0f - wgt) + v1*wgt;
        __syncthreads();
        float ka = 0.f, va = 0.f;
#pragma unroll 8
        for (int ic = 0; ic < 64; ++ic) {
            float kvv = kvs[jl][ic];
            ka += Wks[c][ic]*kvv;
            va += Wvs[c][ic]*kvv;
        }
        kt16[((size_t)(s*8+g)*m + j0 + jloc)*64 + c]   = (_Float16)ka;
        vt16[((size_t)(s*8+g)*64 + c)*m + j0 + jloc]   = (_Float16)va;
        __syncthreads();
    }
}

// ---------------- flash attention v4: LDS dbuf (1 barrier/tile), reg-prefetch, vectored P^T ----------------
// Block = (s,h, 128-query tile); wave w owns i in [w*32, w*32+32).
// QK: A = K frags (LDS), B = Q frags (global, hoisted to regs) -> S^T C-layout
// P^T via wave-private LDS strip: 8 ds_write_b64 + 4 ds_read_b128 (no shuffles)
// PV: A = V^T frags (LDS), B = P^T frags -> O^T C-layout
__global__ __launch_bounds__(256, 2) void k_attn(
    const _Float16* __restrict__ qh, const _Float16* __restrict__ kt16,
    const _Float16* __restrict__ vt16, _Float16* __restrict__ aoh, int n, int m)
{
    __shared__ _Float16 Ks[2][64*72];
    __shared__ _Float16 Vs[2][64*72];
    __shared__ _Float16 Ps[128*72];   // P^T strips; reused as O transpose buffer in epilogue
    int nit = n >> 7;
    int it = blockIdx.x % nit;
    int h  = (blockIdx.x / nit) & 7;
    int s  = blockIdx.x / (nit*8);
    int t  = threadIdx.x;
    int lane = t & 63, w = t >> 6;
    int l15 = lane & 15, quad = lane >> 4;
    int i0 = it*128;

    // Q B-frags: load once from global, keep in registers
    const _Float16* qb = &qh[((size_t)h*n + i0)*64];
    half8 bqv[2][2];
#pragma unroll
    for (int ks = 0; ks < 2; ++ks)
#pragma unroll
        for (int i2 = 0; i2 < 2; ++i2)
            bqv[ks][i2] = *(const half8*)&qb[(w*32 + i2*16 + l15)*64 + ks*32 + quad*8];

    const _Float16* kb = &kt16[(size_t)(s*8+h)*m*64];   // [j][d]
    const _Float16* vb = &vt16[(size_t)(s*8+h)*64*m];   // [d][j]

    // staging coords: thread covers rows (r0, r0+32), 8-halfword column oct
    int r0 = t >> 3, oct = t & 7;

    float lsum[2] = {0.f, 0.f};
    f32x4 oaccT[4][2];
#pragma unroll
    for (int dt = 0; dt < 4; ++dt)
#pragma unroll
        for (int i2 = 0; i2 < 2; ++i2) oaccT[dt][i2] = (f32x4){0.f,0.f,0.f,0.f};

    // prefetch + commit tile 0 into buf 0
    uint4 pk0 = *(const uint4*)&kb[(size_t)r0*64 + oct*8];
    uint4 pk1 = *(const uint4*)&kb[(size_t)(r0+32)*64 + oct*8];
    uint4 pv0 = *(const uint4*)&vb[(size_t)r0*m + oct*8];
    uint4 pv1 = *(const uint4*)&vb[(size_t)(r0+32)*m + oct*8];
    *(uint4*)&Ks[0][r0*72 + oct*8]      = pk0;
    *(uint4*)&Ks[0][(r0+32)*72 + oct*8] = pk1;
    *(uint4*)&Vs[0][r0*72 + oct*8]      = pv0;
    *(uint4*)&Vs[0][(r0+32)*72 + oct*8] = pv1;

    int ntile = m >> 6;
    for (int tk = 0; tk < ntile; ++tk) {
        bool pf = (tk + 1 < ntile);
        if (pf) {   // issue next tile's global loads early (latency hidden by compute)
            pk0 = *(const uint4*)&kb[(size_t)((tk+1)*64 + r0)*64 + oct*8];
            pk1 = *(const uint4*)&kb[(size_t)((tk+1)*64 + r0+32)*64 + oct*8];
            pv0 = *(const uint4*)&vb[(size_t)r0*m + (tk+1)*64 + oct*8];
            pv1 = *(const uint4*)&vb[(size_t)(r0+32)*m + (tk+1)*64 + oct*8];
        }
        __syncthreads();   // buf[tk&1] committed by all waves; prior tile's reads done
        const _Float16* KB = Ks[tk & 1];
        const _Float16* VB = Vs[tk & 1];

        // --- fragment loads from LDS ---
        half8 aqv[2][4];   // K frags [ks][jt]
        half8 avv[2][4];   // V^T frags [ks][dt]
#pragma unroll
        for (int ks = 0; ks < 2; ++ks)
#pragma unroll
            for (int jt = 0; jt < 4; ++jt)
                aqv[ks][jt] = *(const half8*)&KB[(jt*16 + l15)*72 + ks*32 + quad*8];
#pragma unroll
        for (int ks = 0; ks < 2; ++ks)
#pragma unroll
            for (int dt = 0; dt < 4; ++dt)
                avv[ks][dt] = *(const half8*)&VB[(dt*16 + l15)*72 + ks*32 + quad*8];

        // --- S^T = K Q^T over wave's 32-i strip ---
        f32x4 accs[4][2];
#pragma unroll
        for (int jt = 0; jt < 4; ++jt)
#pragma unroll
            for (int i2 = 0; i2 < 2; ++i2) accs[jt][i2] = (f32x4){0.f,0.f,0.f,0.f};
#pragma unroll
        for (int ks = 0; ks < 2; ++ks)
#pragma unroll
            for (int jt = 0; jt < 4; ++jt)
#pragma unroll
                for (int i2 = 0; i2 < 2; ++i2)
                    accs[jt][i2] = __builtin_amdgcn_mfma_f32_16x16x32_f16(
                        aqv[ks][jt], bqv[ks][i2], accs[jt][i2], 0, 0, 0);

        // --- p = exp2(t - MSHIFT); partial row sums; pack + vectored P^T write (wave-private) ---
#pragma unroll
        for (int jt = 0; jt < 4; ++jt)
#pragma unroll
            for (int i2 = 0; i2 < 2; ++i2) {
                f32x4 p;
#pragma unroll
                for (int r = 0; r < 4; ++r) p[r] = __builtin_amdgcn_exp2f(accs[jt][i2][r] - MSHIFT);
                lsum[i2] += (p[0]+p[1]) + (p[2]+p[3]);
                union { fp16x2 h; int i; } c0, c1;
                c0.h = __builtin_amdgcn_cvt_pkrtz(p[0], p[1]);
                c1.h = __builtin_amdgcn_cvt_pkrtz(p[2], p[3]);
                *(int2*)&Ps[(w*32 + i2*16 + l15)*72 + jt*16 + quad*4] = make_int2(c0.i, c1.i);
            }

        // --- O^T += V^T P^T : B-frags straight from Ps ---
#pragma unroll
        for (int ks = 0; ks < 2; ++ks)
#pragma unroll
            for (int i2 = 0; i2 < 2; ++i2) {
                half8 bp = *(const half8*)&Ps[(w*32 + i2*16 + l15)*72 + ks*32 + quad*8];
#pragma unroll
                for (int dt = 0; dt < 4; ++dt)
                    oaccT[dt][i2] = __builtin_amdgcn_mfma_f32_16x16x32_f16(
                        avv[ks][dt], bp, oaccT[dt][i2], 0, 0, 0);
            }

        if (pf) {   // commit next tile into the other buffer (safe: no one reads it this tile)
            int b2 = (tk + 1) & 1;
            *(uint4*)&Ks[b2][r0*72 + oct*8]      = pk0;
            *(uint4*)&Ks[b2][(r0+32)*72 + oct*8] = pk1;
            *(uint4*)&Vs[b2][r0*72 + oct*8]      = pv0;
            *(uint4*)&Vs[b2][(r0+32)*72 + oct*8] = pv1;
        }
    }

    // --- finalize: reduce l across quads, normalize, transpose via Ps strip, store ---
#pragma unroll
    for (int i2 = 0; i2 < 2; ++i2) {
        lsum[i2] += __shfl_xor(lsum[i2], 16, 64);
        lsum[i2] += __shfl_xor(lsum[i2], 32, 64);
    }
    float inv[2] = {1.0f / lsum[0], 1.0f / lsum[1]};
    // wave-private strip of Ps: rows w*32 .. w*32+31 — no barrier needed
#pragma unroll
    for (int dt = 0; dt < 4; ++dt)
#pragma unroll
        for (int i2 = 0; i2 < 2; ++i2)
#pragma unroll
            for (int r = 0; r < 4; ++r)
                Ps[(w*32 + i2*16 + l15)*72 + dt*16 + quad*4 + r]
                    = (_Float16)(oaccT[dt][i2][r] * inv[i2]);
    {
        int row = w*32 + (lane >> 1);
        int dbase = (lane & 1) * 32;
        size_t gbase = (size_t)(i0 + row)*1024 + s*512 + h*64 + dbase;
#pragma unroll
        for (int k2 = 0; k2 < 4; ++k2) {
            uint4 v = *(uint4*)&Ps[row*72 + dbase + k2*8];
            *(uint4*)&aoh[gbase + k2*8] = v;
        }
    }
}

// ---------------- Wo GEMM, f16 MFMA ----------------
__global__ __launch_bounds__(256) void k_out(
    const _Float16* __restrict__ aoh, const _Float16* __restrict__ Woh,
    const float* __restrict__ bo, float* __restrict__ out, int n)
{
    __shared__ _Float16 As[64*72];   // [i][k]
    __shared__ _Float16 Ws[64*72];   // [d][k]
    int i0 = blockIdx.x*64, d0 = blockIdx.y*64;
    int t = threadIdx.x;
    int lane = t & 63, w = t >> 6;
    int l15 = lane & 15, quad = lane >> 4;
    f32x4 oacc[4];
#pragma unroll
    for (int dt = 0; dt < 4; ++dt) oacc[dt] = (f32x4){0.f,0.f,0.f,0.f};

    for (int kc = 0; kc < 16; ++kc) {
        int cbase = (kc & 7) * 64;
        __syncthreads();
#pragma unroll
        for (int r = 0; r < 2; ++r) {
            int c = t + 256*r;
            int row = c >> 3, oct = c & 7;
            *(uint4*)&As[row*72 + oct*8] = *(const uint4*)&aoh[(size_t)(i0+row)*1024 + kc*64 + oct*8];
            *(uint4*)&Ws[row*72 + oct*8] = *(const uint4*)&Woh[(size_t)(d0+row)*DIMC + cbase + oct*8];
        }
        __syncthreads();
#pragma unroll
        for (int ks = 0; ks < 2; ++ks) {
            half8 aq = *(const half8*)&As[(w*16 + l15)*72 + ks*32 + quad*8];
#pragma unroll
            for (int dt = 0; dt < 4; ++dt) {
                half8 bw = *(const half8*)&Ws[(dt*16 + l15)*72 + ks*32 + quad*8];
                oacc[dt] = __builtin_amdgcn_mfma_f32_16x16x32_f16(aq, bw, oacc[dt], 0, 0, 0);
            }
        }
    }
#pragma unroll
    for (int dt = 0; dt < 4; ++dt) {
        float bias = bo[d0 + dt*16 + l15];
#pragma unroll
        for (int r = 0; r < 4; ++r)
            out[(size_t)(i0 + w*16 + quad*4 + r)*DIMC + d0 + dt*16 + l15]
                = bias + 0.5f*oacc[dt][r];
    }
}

extern "C" void kernel_launch(void* const* d_in, const int* in_sizes, int n_in,
                              void* d_out, int out_size, void* d_ws, size_t ws_size,
                              hipStream_t stream)
{
    const float* x   = (const float*)d_in[0];
    const float* px  = (const float*)d_in[1];
    const float* Wq  = (const float*)d_in[2];
    const float* Wk  = (const float*)d_in[3];
    const float* Wv  = (const float*)d_in[4];
    const float* Wo  = (const float*)d_in[5];
    const float* bo  = (const float*)d_in[6];
    const float* Wdw = (const float*)d_in[7];
    const float* bdw = (const float*)d_in[8];
    const float* Wp  = (const float*)d_in[9];
    float* out = (float*)d_out;
    int n = in_sizes[0] / DIMC;     // 4096
    int m = n / 4;                  // 1024

    float* ws  = (float*)d_ws;
    float* q    = ws;                                 // 512*n f32
    int*   x0i  = (int*)(q + (size_t)512*n);          // 8*m
    float* w1f  = (float*)(x0i + 8*m);                // 8*m
    _Float16* qhf  = (_Float16*)(w1f + 8*m);          // 8*n*64 f16   [h][i][d]
    _Float16* kt16 = qhf + (size_t)8*n*64;            // 2*8*m*64 f16 [s][h][j][d]
    _Float16* vt16 = kt16 + (size_t)16*m*64;          // 2*8*m*64 f16 [s][h][d][j]
    _Float16* aoh  = vt16 + (size_t)16*m*64;          // n*1024 f16   [i][c']
    _Float16* Woh  = aoh + (size_t)n*1024;            // 512*512 f16  [d][c]

    k_wcvt <<<128,              256, 0, stream>>>(Wo, Woh);
    k_qconv<<<dim3(8, n/64),    256, 0, stream>>>(x, px, Wq, q, qhf, n);
    k_off  <<<8*(m/32),         256, 0, stream>>>(q, Wdw, bdw, Wp, x0i, w1f, n, m);
    k_kv   <<<2*8*(m/64),       256, 0, stream>>>(x, px, Wk, Wv, x0i, w1f, kt16, vt16, n, m);
    k_attn <<<2*8*(n/128),      256, 0, stream>>>(qhf, kt16, vt16, aoh, n, m);
    k_out  <<<dim3(n/64, 8),    256, 0, stream>>>(aoh, Woh, bo, out, n);
}

// Round 9
// 190.146 us; speedup vs baseline: 1.2228x; 1.0291x over previous
//
#include <hip/hip_runtime.h>
#include <math.h>

#define DIMC 512
#define NG 8
// q pre-scale: 64^-0.5 * log2(e)  (so scores come out in exp2 units)
#define QSCALE 0.18033688011112042f
// softmax fixed shift: 5 * log2(e)
#define MSHIFT 7.2134752044448170f

typedef _Float16 half8 __attribute__((ext_vector_type(8)));
typedef __fp16 fp16x2 __attribute__((ext_vector_type(2)));
typedef float f32x4 __attribute__((ext_vector_type(4)));

// build a half8 MFMA fragment from 8 consecutive global f32
__device__ __forceinline__ half8 frag_f32(const float* p) {
    float4 a = *(const float4*)p;
    float4 b = *(const float4*)(p + 4);
    union { fp16x2 h2[4]; half8 h8; } u;
    u.h2[0] = __builtin_amdgcn_cvt_pkrtz(a.x, a.y);
    u.h2[1] = __builtin_amdgcn_cvt_pkrtz(a.z, a.w);
    u.h2[2] = __builtin_amdgcn_cvt_pkrtz(b.x, b.y);
    u.h2[3] = __builtin_amdgcn_cvt_pkrtz(b.z, b.w);
    return u.h8;
}

// ---------------- Wo f32 -> f16 cast (native [d][c] layout == MFMA B layout) ----------------
__global__ __launch_bounds__(256) void k_wcvt(const float* __restrict__ Wo, _Float16* __restrict__ Woh) {
    int idx = (blockIdx.x*256 + threadIdx.x) * 8;
    float4 a = *(const float4*)&Wo[idx];
    float4 b = *(const float4*)&Wo[idx+4];
    union { _Float16 h[8]; uint4 v; } pk;
    pk.h[0]=(_Float16)a.x; pk.h[1]=(_Float16)a.y; pk.h[2]=(_Float16)a.z; pk.h[3]=(_Float16)a.w;
    pk.h[4]=(_Float16)b.x; pk.h[5]=(_Float16)b.y; pk.h[6]=(_Float16)b.z; pk.h[7]=(_Float16)b.w;
    *(uint4*)&Woh[idx] = pk.v;
}

// ---------------- q = grouped 1x1 conv, f16 MFMA, zero-LDS main loop ----------------
// A = X rows (global f32 -> f16 frags), B = Wq rows (native [oc][k] = B layout).
// Outputs: q fp32 [oc][i] and qh f16 [h][i][d] (QSCALE applied), via one LDS transpose.
__global__ __launch_bounds__(256) void k_qconv(
    const float* __restrict__ x, const float* __restrict__ px,
    const float* __restrict__ Wq, float* __restrict__ q, _Float16* __restrict__ qh, int n)
{
    __shared__ float Os[64*69];      // [i][oc], stride 69 (odd -> 2-way banks both phases)
    int g  = blockIdx.x;             // 0..7 == head
    int i0 = blockIdx.y * 64;
    int t  = threadIdx.x;
    int lane = t & 63, w = t >> 6;
    int l15 = lane & 15, quad = lane >> 4;
    const float* SRC = (g < 4) ? px : x;    // concat puts prev first
    int cbase = (g & 3) * 128;

    // A-frags: wave's 16 rows i = i0 + w*16 + l15; k = ks*32 + quad*8
    half8 af[4];
#pragma unroll
    for (int ks = 0; ks < 4; ++ks)
        af[ks] = frag_f32(&SRC[(size_t)(i0 + w*16 + l15)*DIMC + cbase + ks*32 + quad*8]);

    f32x4 acc[4];
#pragma unroll
    for (int nt = 0; nt < 4; ++nt) acc[nt] = (f32x4){0.f,0.f,0.f,0.f};
#pragma unroll
    for (int ks = 0; ks < 4; ++ks)
#pragma unroll
        for (int nt = 0; nt < 4; ++nt) {
            half8 bf = frag_f32(&Wq[(size_t)(g*64 + nt*16 + l15)*128 + ks*32 + quad*8]);
            acc[nt] = __builtin_amdgcn_mfma_f32_16x16x32_f16(af[ks], bf, acc[nt], 0, 0, 0);
        }

    // C-layout -> Os[i][oc]
#pragma unroll
    for (int nt = 0; nt < 4; ++nt)
#pragma unroll
        for (int r = 0; r < 4; ++r)
            Os[(w*16 + quad*4 + r)*69 + nt*16 + l15] = acc[nt][r];
    __syncthreads();
    // q fp32 channel-major, coalesced over lane=i
    {
        int i = t & 63, ocb = (t >> 6) * 16;
#pragma unroll
        for (int u = 0; u < 16; ++u)
            q[(size_t)(g*64 + ocb + u)*n + i0 + i] = Os[i*69 + ocb + u];
    }
    // qh f16 [h][i][d] with QSCALE
    {
        int i = t >> 2, cq = t & 3;
        union { _Float16 h[16]; uint4 v[2]; } pk;
#pragma unroll
        for (int u = 0; u < 16; ++u) pk.h[u] = (_Float16)(Os[i*69 + cq*16 + u] * QSCALE);
        uint4* dst = (uint4*)&qh[((size_t)g*n + i0 + i)*64 + cq*16];
        dst[0] = pk.v[0]; dst[1] = pk.v[1];
    }
}

// ---------------- offset net ----------------
#define SW 136
__global__ __launch_bounds__(256) void k_off(
    const float* __restrict__ q, const float* __restrict__ Wdw,
    const float* __restrict__ bdw, const float* __restrict__ Wp,
    int* __restrict__ x0i, float* __restrict__ w1f, int n, int m)
{
    __shared__ float qs[64][SW];
    __shared__ float part[8][36];
    int g  = blockIdx.x & 7;
    int j0 = (blockIdx.x >> 3) * 32;
    int t  = threadIdx.x;
    int lane = t & 63, wv = t >> 6;
    int pbase = 4*j0 - 1;
#pragma unroll
    for (int rr = 0; rr < 16; ++rr) {
        int row = rr*4 + wv;
        const float* src = &q[(size_t)(g*64 + row)*n];
#pragma unroll
        for (int cc = 0; cc < 3; ++cc) {
            int col = cc*64 + lane;
            if (col < SW) {
                int p = pbase + col;
                qs[row][col] = (p >= 0 && p < n) ? src[p] : 0.f;
            }
        }
    }
    __syncthreads();
    int j  = t & 31, cg = t >> 5;
    float acc = 0.f;
#pragma unroll
    for (int cc = 0; cc < 8; ++cc) {
        int c = cg*8 + cc;
        float h = bdw[c];
#pragma unroll
        for (int tt = 0; tt < 6; ++tt)
            h += Wdw[c*6 + tt] * qs[c][4*j + tt];
        float ge = 0.5f * h * (1.0f + erff(h * 0.70710678118654752f));  // exact gelu
        acc += Wp[c] * ge;
    }
    part[cg][j] = acc;
    __syncthreads();
    if (t < 32) {
        float off = 0.f;
#pragma unroll
        for (int cg2 = 0; cg2 < 8; ++cg2) off += part[cg2][t];
        off = tanhf(off) * 4.0f;
        int jg = j0 + t;
        float vg  = 2.0f * ((float)jg + off) / (float)(m - 1) - 1.0f;
        float pos = ((vg + 1.0f) * (float)n - 1.0f) * 0.5f;
        float x0  = floorf(pos);
        x0i[g*m + jg] = (int)x0;
        w1f[g*m + jg] = pos - x0;
    }
}

// ---------------- grid-sample + k/v convs, f16 MFMA ----------------
// Block = (s,g, 32 j's). Gather kv tile -> f16 LDS (1 barrier), A = kv, B = Wk/Wv from global.
__global__ __launch_bounds__(256) void k_kv(
    const float* __restrict__ x, const float* __restrict__ px,
    const float* __restrict__ Wk, const float* __restrict__ Wv,
    const int* __restrict__ x0i, const float* __restrict__ w1f,
    _Float16* __restrict__ kt16, _Float16* __restrict__ vt16, int n, int m)
{
    __shared__ _Float16 kvs[32*72];   // [j][c] f16
    int nj = m >> 5;                  // 32
    int jc = blockIdx.x % nj;
    int g  = (blockIdx.x / nj) & 7;
    int s  = blockIdx.x / (nj*8);
    int t  = threadIdx.x;
    int lane = t & 63, w = t >> 6;
    int l15 = lane & 15, quad = lane >> 4;
    int j0 = jc*32;
    const float* SRC = s ? x : px;    // kv_in = concat([prev, cur], axis=0)

    // gather (prefetch all loads, then lerp+commit)
    float g0[8], g1[8], wg[8];
#pragma unroll
    for (int jj = 0; jj < 8; ++jj) {
        int j = jj*4 + w;
        int ii = x0i[g*m + j0 + j];
        wg[jj] = w1f[g*m + j0 + j];
        g0[jj] = (ii   >= 0 && ii   < n) ? SRC[(size_t)ii*DIMC + g*64 + lane]     : 0.f;
        g1[jj] = (ii+1 >= 0 && ii+1 < n) ? SRC[(size_t)(ii+1)*DIMC + g*64 + lane] : 0.f;
    }
#pragma unroll
    for (int jj = 0; jj < 8; ++jj)
        kvs[(jj*4 + w)*72 + lane] = (_Float16)(g0[jj]*(1.0f - wg[jj]) + g1[jj]*wg[jj]);
    __syncthreads();

    // A-frags from kvs, B-frags from global Wk/Wv; wave w owns oc-strip w*16
    half8 af[2][2];   // [mt][ks]
#pragma unroll
    for (int mt = 0; mt < 2; ++mt)
#pragma unroll
        for (int ks = 0; ks < 2; ++ks)
            af[mt][ks] = *(const half8*)&kvs[(mt*16 + l15)*72 + ks*32 + quad*8];
    f32x4 ack[2], acv[2];
#pragma unroll
    for (int mt = 0; mt < 2; ++mt) { ack[mt] = (f32x4){0.f,0.f,0.f,0.f}; acv[mt] = (f32x4){0.f,0.f,0.f,0.f}; }
#pragma unroll
    for (int ks = 0; ks < 2; ++ks) {
        half8 bk = frag_f32(&Wk[(size_t)(g*64 + w*16 + l15)*64 + ks*32 + quad*8]);
        half8 bv = frag_f32(&Wv[(size_t)(g*64 + w*16 + l15)*64 + ks*32 + quad*8]);
#pragma unroll
        for (int mt = 0; mt < 2; ++mt) {
            ack[mt] = __builtin_amdgcn_mfma_f32_16x16x32_f16(af[mt][ks], bk, ack[mt], 0, 0, 0);
            acv[mt] = __builtin_amdgcn_mfma_f32_16x16x32_f16(af[mt][ks], bv, acv[mt], 0, 0, 0);
        }
    }
    // store: lane holds j = mt*16+quad*4+r, oc = w*16+l15
    size_t hb = (size_t)(s*8 + g);
#pragma unroll
    for (int mt = 0; mt < 2; ++mt) {
#pragma unroll
        for (int r = 0; r < 4; ++r)
            kt16[(hb*m + j0 + mt*16 + quad*4 + r)*64 + w*16 + l15] = (_Float16)ack[mt][r];
        union { fp16x2 h2[2]; uint2 v; } pv;
        pv.h2[0] = __builtin_amdgcn_cvt_pkrtz(acv[mt][0], acv[mt][1]);
        pv.h2[1] = __builtin_amdgcn_cvt_pkrtz(acv[mt][2], acv[mt][3]);
        *(uint2*)&vt16[(hb*64 + w*16 + l15)*m + j0 + mt*16 + quad*4] = pv.v;   // 4 consecutive j
    }
}

// ---------------- flash attention v5: K frags direct from global; V LDS-dbuf; vectored P^T ----------------
__global__ __launch_bounds__(256, 2) void k_attn(
    const _Float16* __restrict__ qh, const _Float16* __restrict__ kt16,
    const _Float16* __restrict__ vt16, _Float16* __restrict__ aoh, int n, int m)
{
    __shared__ _Float16 Vs[2][64*72];
    __shared__ _Float16 Ps[128*72];   // P^T strips; reused as O transpose buffer in epilogue
    int nit = n >> 7;
    int it = blockIdx.x % nit;
    int h  = (blockIdx.x / nit) & 7;
    int s  = blockIdx.x / (nit*8);
    int t  = threadIdx.x;
    int lane = t & 63, w = t >> 6;
    int l15 = lane & 15, quad = lane >> 4;
    int i0 = it*128;

    // Q B-frags: load once from global, keep in registers
    const _Float16* qb = &qh[((size_t)h*n + i0)*64];
    half8 bqv[2][2];
#pragma unroll
    for (int ks = 0; ks < 2; ++ks)
#pragma unroll
        for (int i2 = 0; i2 < 2; ++i2)
            bqv[ks][i2] = *(const half8*)&qb[(w*32 + i2*16 + l15)*64 + ks*32 + quad*8];

    const _Float16* kb = &kt16[(size_t)(s*8+h)*m*64];   // [j][d]
    const _Float16* vb = &vt16[(size_t)(s*8+h)*64*m];   // [d][j]

    int r0 = t >> 3, oct = t & 7;

    float lsum[2] = {0.f, 0.f};
    f32x4 oaccT[4][2];
#pragma unroll
    for (int dt = 0; dt < 4; ++dt)
#pragma unroll
        for (int i2 = 0; i2 < 2; ++i2) oaccT[dt][i2] = (f32x4){0.f,0.f,0.f,0.f};

    // prefetch + commit V tile 0 into buf 0
    uint4 pv0 = *(const uint4*)&vb[(size_t)r0*m + oct*8];
    uint4 pv1 = *(const uint4*)&vb[(size_t)(r0+32)*m + oct*8];
    *(uint4*)&Vs[0][r0*72 + oct*8]      = pv0;
    *(uint4*)&Vs[0][(r0+32)*72 + oct*8] = pv1;

    int ntile = m >> 6;
    for (int tk = 0; tk < ntile; ++tk) {
        bool pf = (tk + 1 < ntile);
        if (pf) {   // next V tile's global loads, latency hidden by compute
            pv0 = *(const uint4*)&vb[(size_t)r0*m + (tk+1)*64 + oct*8];
            pv1 = *(const uint4*)&vb[(size_t)(r0+32)*m + (tk+1)*64 + oct*8];
        }
        // K frags for this tile: direct global (L1-resident 8 KB tile)
        half8 aqv[2][4];
#pragma unroll
        for (int ks = 0; ks < 2; ++ks)
#pragma unroll
            for (int jt = 0; jt < 4; ++jt)
                aqv[ks][jt] = *(const half8*)&kb[(size_t)(tk*64 + jt*16 + l15)*64 + ks*32 + quad*8];

        __syncthreads();   // V buf[tk&1] committed; prior tile's reads done
        const _Float16* VB = Vs[tk & 1];
        half8 avv[2][4];
#pragma unroll
        for (int ks = 0; ks < 2; ++ks)
#pragma unroll
            for (int dt = 0; dt < 4; ++dt)
                avv[ks][dt] = *(const half8*)&VB[(dt*16 + l15)*72 + ks*32 + quad*8];

        // --- S^T = K Q^T over wave's 32-i strip ---
        f32x4 accs[4][2];
#pragma unroll
        for (int jt = 0; jt < 4; ++jt)
#pragma unroll
            for (int i2 = 0; i2 < 2; ++i2) accs[jt][i2] = (f32x4){0.f,0.f,0.f,0.f};
#pragma unroll
        for (int ks = 0; ks < 2; ++ks)
#pragma unroll
            for (int jt = 0; jt < 4; ++jt)
#pragma unroll
                for (int i2 = 0; i2 < 2; ++i2)
                    accs[jt][i2] = __builtin_amdgcn_mfma_f32_16x16x32_f16(
                        aqv[ks][jt], bqv[ks][i2], accs[jt][i2], 0, 0, 0);

        // --- p = exp2(t - MSHIFT); partial row sums; pack + vectored P^T write (wave-private) ---
#pragma unroll
        for (int jt = 0; jt < 4; ++jt)
#pragma unroll
            for (int i2 = 0; i2 < 2; ++i2) {
                f32x4 p;
#pragma unroll
                for (int r = 0; r < 4; ++r) p[r] = __builtin_amdgcn_exp2f(accs[jt][i2][r] - MSHIFT);
                lsum[i2] += (p[0]+p[1]) + (p[2]+p[3]);
                union { fp16x2 h; int i; } c0, c1;
                c0.h = __builtin_amdgcn_cvt_pkrtz(p[0], p[1]);
                c1.h = __builtin_amdgcn_cvt_pkrtz(p[2], p[3]);
                *(int2*)&Ps[(w*32 + i2*16 + l15)*72 + jt*16 + quad*4] = make_int2(c0.i, c1.i);
            }

        // --- O^T += V^T P^T ---
#pragma unroll
        for (int ks = 0; ks < 2; ++ks)
#pragma unroll
            for (int i2 = 0; i2 < 2; ++i2) {
                half8 bp = *(const half8*)&Ps[(w*32 + i2*16 + l15)*72 + ks*32 + quad*8];
#pragma unroll
                for (int dt = 0; dt < 4; ++dt)
                    oaccT[dt][i2] = __builtin_amdgcn_mfma_f32_16x16x32_f16(
                        avv[ks][dt], bp, oaccT[dt][i2], 0, 0, 0);
            }

        if (pf) {   // commit next V tile into the other buffer
            int b2 = (tk + 1) & 1;
            *(uint4*)&Vs[b2][r0*72 + oct*8]      = pv0;
            *(uint4*)&Vs[b2][(r0+32)*72 + oct*8] = pv1;
        }
    }

    // --- finalize ---
#pragma unroll
    for (int i2 = 0; i2 < 2; ++i2) {
        lsum[i2] += __shfl_xor(lsum[i2], 16, 64);
        lsum[i2] += __shfl_xor(lsum[i2], 32, 64);
    }
    float inv[2] = {1.0f / lsum[0], 1.0f / lsum[1]};
#pragma unroll
    for (int dt = 0; dt < 4; ++dt)
#pragma unroll
        for (int i2 = 0; i2 < 2; ++i2)
#pragma unroll
            for (int r = 0; r < 4; ++r)
                Ps[(w*32 + i2*16 + l15)*72 + dt*16 + quad*4 + r]
                    = (_Float16)(oaccT[dt][i2][r] * inv[i2]);
    {
        int row = w*32 + (lane >> 1);
        int dbase = (lane & 1) * 32;
        size_t gbase = (size_t)(i0 + row)*1024 + s*512 + h*64 + dbase;
#pragma unroll
        for (int k2 = 0; k2 < 4; ++k2) {
            uint4 v = *(uint4*)&Ps[row*72 + dbase + k2*8];
            *(uint4*)&aoh[gbase + k2*8] = v;
        }
    }
}

// ---------------- Wo GEMM, f16 MFMA, zero-LDS (A/B frags direct from global) ----------------
__global__ __launch_bounds__(256) void k_out(
    const _Float16* __restrict__ aoh, const _Float16* __restrict__ Woh,
    const float* __restrict__ bo, float* __restrict__ out, int n)
{
    int i0 = blockIdx.x*64, d0 = blockIdx.y*64;
    int t = threadIdx.x;
    int lane = t & 63, w = t >> 6;
    int l15 = lane & 15, quad = lane >> 4;
    f32x4 oacc[4];
#pragma unroll
    for (int dt = 0; dt < 4; ++dt) oacc[dt] = (f32x4){0.f,0.f,0.f,0.f};

    const _Float16* arow = &aoh[(size_t)(i0 + w*16 + l15)*1024 + quad*8];
#pragma unroll 4
    for (int ks = 0; ks < 32; ++ks) {            // K' = 1024
        half8 aq = *(const half8*)&arow[ks*32];
        int cbase = (ks & 15) * 32;              // c = c' & 511
#pragma unroll
        for (int dt = 0; dt < 4; ++dt) {
            half8 bw = *(const half8*)&Woh[(size_t)(d0 + dt*16 + l15)*DIMC + cbase + quad*8];
            oacc[dt] = __builtin_amdgcn_mfma_f32_16x16x32_f16(aq, bw, oacc[dt], 0, 0, 0);
        }
    }
#pragma unroll
    for (int dt = 0; dt < 4; ++dt) {
        float bias = bo[d0 + dt*16 + l15];
#pragma unroll
        for (int r = 0; r < 4; ++r)
            out[(size_t)(i0 + w*16 + quad*4 + r)*DIMC + d0 + dt*16 + l15]
                = bias + 0.5f*oacc[dt][r];
    }
}

extern "C" void kernel_launch(void* const* d_in, const int* in_sizes, int n_in,
                              void* d_out, int out_size, void* d_ws, size_t ws_size,
                              hipStream_t stream)
{
    const float* x   = (const float*)d_in[0];
    const float* px  = (const float*)d_in[1];
    const float* Wq  = (const float*)d_in[2];
    const float* Wk  = (const float*)d_in[3];
    const float* Wv  = (const float*)d_in[4];
    const float* Wo  = (const float*)d_in[5];
    const float* bo  = (const float*)d_in[6];
    const float* Wdw = (const float*)d_in[7];
    const float* bdw = (const float*)d_in[8];
    const float* Wp  = (const float*)d_in[9];
    float* out = (float*)d_out;
    int n = in_sizes[0] / DIMC;     // 4096
    int m = n / 4;                  // 1024

    float* ws  = (float*)d_ws;
    float* q    = ws;                                 // 512*n f32
    int*   x0i  = (int*)(q + (size_t)512*n);          // 8*m
    float* w1f  = (float*)(x0i + 8*m);                // 8*m
    _Float16* qhf  = (_Float16*)(w1f + 8*m);          // 8*n*64 f16   [h][i][d]
    _Float16* kt16 = qhf + (size_t)8*n*64;            // 2*8*m*64 f16 [s][h][j][d]
    _Float16* vt16 = kt16 + (size_t)16*m*64;          // 2*8*m*64 f16 [s][h][d][j]
    _Float16* aoh  = vt16 + (size_t)16*m*64;          // n*1024 f16   [i][c']
    _Float16* Woh  = aoh + (size_t)n*1024;            // 512*512 f16  [d][c]

    k_wcvt <<<128,              256, 0, stream>>>(Wo, Woh);
    k_qconv<<<dim3(8, n/64),    256, 0, stream>>>(x, px, Wq, q, qhf, n);
    k_off  <<<8*(m/32),         256, 0, stream>>>(q, Wdw, bdw, Wp, x0i, w1f, n, m);
    k_kv   <<<2*8*(m/32),       256, 0, stream>>>(x, px, Wk, Wv, x0i, w1f, kt16, vt16, n, m);
    k_attn <<<2*8*(n/128),      256, 0, stream>>>(qhf, kt16, vt16, aoh, n, m);
    k_out  <<<dim3(n/64, 8),    256, 0, stream>>>(aoh, Woh, bo, out, n);
}

// Round 10
// 173.814 us; speedup vs baseline: 1.3377x; 1.0940x over previous
//
#include <hip/hip_runtime.h>
#include <math.h>

#define DIMC 512
#define NG 8
// q pre-scale: 64^-0.5 * log2(e)  (so scores come out in exp2 units)
#define QSCALE 0.18033688011112042f
// softmax fixed shift: 5 * log2(e)
#define MSHIFT 7.2134752044448170f

typedef _Float16 half8 __attribute__((ext_vector_type(8)));
typedef __fp16 fp16x2 __attribute__((ext_vector_type(2)));
typedef float f32x4 __attribute__((ext_vector_type(4)));

// build a half8 MFMA fragment from 8 consecutive global f32
__device__ __forceinline__ half8 frag_f32(const float* p) {
    float4 a = *(const float4*)p;
    float4 b = *(const float4*)(p + 4);
    union { fp16x2 h2[4]; half8 h8; } u;
    u.h2[0] = __builtin_amdgcn_cvt_pkrtz(a.x, a.y);
    u.h2[1] = __builtin_amdgcn_cvt_pkrtz(a.z, a.w);
    u.h2[2] = __builtin_amdgcn_cvt_pkrtz(b.x, b.y);
    u.h2[3] = __builtin_amdgcn_cvt_pkrtz(b.z, b.w);
    return u.h8;
}

// ---------------- fused: q conv (f16 MFMA) + qh emit + offset net from LDS ----------------
// Block = (g, 128-position tile). Wave w owns i-strip [P0+w*32, +32).
// Halo q at p=P0-1 / P0+128 recomputed exactly in fp32 (zero-padded at edges).
__global__ __launch_bounds__(256) void k_qoff(
    const float* __restrict__ x, const float* __restrict__ px,
    const float* __restrict__ Wq, const float* __restrict__ Wdw,
    const float* __restrict__ bdw, const float* __restrict__ Wp,
    _Float16* __restrict__ qh, int* __restrict__ x0i, float* __restrict__ w1f,
    int n, int m)
{
    __shared__ float Os[128*69];    // [i][oc], stride 69
    __shared__ float hl[2][64];     // halo q: [side][c]
    __shared__ float part[8][36];
    int g  = blockIdx.x & 7;
    int jt = blockIdx.x >> 3;
    int P0 = jt*128, j0 = jt*32;
    int t  = threadIdx.x;
    int lane = t & 63, w = t >> 6;
    int l15 = lane & 15, quad = lane >> 4;
    const float* SRC = (g < 4) ? px : x;    // concat puts prev first
    int cbase = (g & 3) * 128;

    // halo q (fp32 exact), 128 threads; overlaps with MFMA section below
    if (t < 128) {
        int side = t >> 6, c = t & 63;
        int p = P0 + (side ? 128 : -1);
        float hsum = 0.f;
        if (p >= 0 && p < n) {
            const float* xr = &SRC[(size_t)p*DIMC + cbase];
            const float* wr = &Wq[(size_t)(g*64 + c)*128];
#pragma unroll 8
            for (int k = 0; k < 32; ++k) {
                float4 xv = *(const float4*)&xr[k*4];
                float4 wv = *(const float4*)&wr[k*4];
                hsum += xv.x*wv.x + xv.y*wv.y + xv.z*wv.z + xv.w*wv.w;
            }
        }
        hl[side][c] = hsum;
    }

    // main q tile via f16 MFMA
    half8 af[2][4];
#pragma unroll
    for (int mt = 0; mt < 2; ++mt)
#pragma unroll
        for (int ks = 0; ks < 4; ++ks)
            af[mt][ks] = frag_f32(&SRC[(size_t)(P0 + w*32 + mt*16 + l15)*DIMC + cbase + ks*32 + quad*8]);
    f32x4 acc[2][4];
#pragma unroll
    for (int mt = 0; mt < 2; ++mt)
#pragma unroll
        for (int nt = 0; nt < 4; ++nt) acc[mt][nt] = (f32x4){0.f,0.f,0.f,0.f};
#pragma unroll
    for (int ks = 0; ks < 4; ++ks)
#pragma unroll
        for (int nt = 0; nt < 4; ++nt) {
            half8 bf = frag_f32(&Wq[(size_t)(g*64 + nt*16 + l15)*128 + ks*32 + quad*8]);
#pragma unroll
            for (int mt = 0; mt < 2; ++mt)
                acc[mt][nt] = __builtin_amdgcn_mfma_f32_16x16x32_f16(af[mt][ks], bf, acc[mt][nt], 0, 0, 0);
        }
    // C-layout -> Os[i][oc]
#pragma unroll
    for (int mt = 0; mt < 2; ++mt)
#pragma unroll
        for (int nt = 0; nt < 4; ++nt)
#pragma unroll
            for (int r = 0; r < 4; ++r)
                Os[(w*32 + mt*16 + quad*4 + r)*69 + nt*16 + l15] = acc[mt][nt][r];
    __syncthreads();

    // qh f16 [h][i][d] with QSCALE: thread covers half a row (32 f16)
    {
        int i = t >> 1, hf = t & 1;
        union { _Float16 h[32]; uint4 v[4]; } pk;
#pragma unroll
        for (int u = 0; u < 32; ++u) pk.h[u] = (_Float16)(Os[i*69 + hf*32 + u] * QSCALE);
        uint4* dst = (uint4*)&qh[((size_t)g*n + P0 + i)*64 + hf*32];
        dst[0] = pk.v[0]; dst[1] = pk.v[1]; dst[2] = pk.v[2]; dst[3] = pk.v[3];
    }

    // offset net straight from LDS: thread = (j = t&31, cg = t>>5)
    {
        int j = t & 31, cg = t >> 5;
        float accо = 0.f;
#pragma unroll
        for (int cc = 0; cc < 8; ++cc) {
            int c = cg*8 + cc;
            float h = bdw[c];
#pragma unroll
            for (int tt = 0; tt < 6; ++tt) {
                int lp = 4*j + tt - 1;
                float val = (lp < 0) ? hl[0][c] : (lp >= 128 ? hl[1][c] : Os[lp*69 + c]);
                h += Wdw[c*6 + tt] * val;
            }
            float ge = 0.5f * h * (1.0f + erff(h * 0.70710678118654752f));  // exact gelu
            accо += Wp[c] * ge;
        }
        part[cg][j] = accо;
    }
    __syncthreads();
    if (t < 32) {
        float off = 0.f;
#pragma unroll
        for (int cg2 = 0; cg2 < 8; ++cg2) off += part[cg2][t];
        off = tanhf(off) * 4.0f;
        int jg = j0 + t;
        float vg  = 2.0f * ((float)jg + off) / (float)(m - 1) - 1.0f;
        float pos = ((vg + 1.0f) * (float)n - 1.0f) * 0.5f;
        float x0  = floorf(pos);
        x0i[g*m + jg] = (int)x0;
        w1f[g*m + jg] = pos - x0;
    }
}

// ---------------- grid-sample + k/v convs, f16 MFMA; prologue: Wo f32->f16 cast ----------------
__global__ __launch_bounds__(256) void k_kv(
    const float* __restrict__ x, const float* __restrict__ px,
    const float* __restrict__ Wk, const float* __restrict__ Wv,
    const float* __restrict__ Wo, const int* __restrict__ x0i,
    const float* __restrict__ w1f, _Float16* __restrict__ kt16,
    _Float16* __restrict__ vt16, _Float16* __restrict__ Woh, int n, int m)
{
    __shared__ _Float16 kvs[32*72];   // [j][c] f16
    int nj = m >> 5;                  // 32
    int jc = blockIdx.x % nj;
    int g  = (blockIdx.x / nj) & 7;
    int s  = blockIdx.x / (nj*8);
    int t  = threadIdx.x;
    int lane = t & 63, w = t >> 6;
    int l15 = lane & 15, quad = lane >> 4;
    int j0 = jc*32;
    const float* SRC = s ? x : px;    // kv_in = concat([prev, cur], axis=0)

    // Wo cast (first 128 blocks, 2048 elems each); k_out runs after us on the stream
    if (blockIdx.x < 128) {
        int idx = blockIdx.x*2048 + t*8;
        float4 a = *(const float4*)&Wo[idx];
        float4 b = *(const float4*)&Wo[idx+4];
        union { fp16x2 h2[4]; uint4 v; } pk;
        pk.h2[0] = __builtin_amdgcn_cvt_pkrtz(a.x, a.y);
        pk.h2[1] = __builtin_amdgcn_cvt_pkrtz(a.z, a.w);
        pk.h2[2] = __builtin_amdgcn_cvt_pkrtz(b.x, b.y);
        pk.h2[3] = __builtin_amdgcn_cvt_pkrtz(b.z, b.w);
        *(uint4*)&Woh[idx] = pk.v;
    }

    // gather (prefetch all loads, then lerp+commit)
    float g0[8], g1[8], wg[8];
#pragma unroll
    for (int jj = 0; jj < 8; ++jj) {
        int j = jj*4 + w;
        int ii = x0i[g*m + j0 + j];
        wg[jj] = w1f[g*m + j0 + j];
        g0[jj] = (ii   >= 0 && ii   < n) ? SRC[(size_t)ii*DIMC + g*64 + lane]     : 0.f;
        g1[jj] = (ii+1 >= 0 && ii+1 < n) ? SRC[(size_t)(ii+1)*DIMC + g*64 + lane] : 0.f;
    }
#pragma unroll
    for (int jj = 0; jj < 8; ++jj)
        kvs[(jj*4 + w)*72 + lane] = (_Float16)(g0[jj]*(1.0f - wg[jj]) + g1[jj]*wg[jj]);
    __syncthreads();

    // A-frags from kvs, B-frags from global Wk/Wv; wave w owns oc-strip w*16
    half8 af[2][2];   // [mt][ks]
#pragma unroll
    for (int mt = 0; mt < 2; ++mt)
#pragma unroll
        for (int ks = 0; ks < 2; ++ks)
            af[mt][ks] = *(const half8*)&kvs[(mt*16 + l15)*72 + ks*32 + quad*8];
    f32x4 ack[2], acv[2];
#pragma unroll
    for (int mt = 0; mt < 2; ++mt) { ack[mt] = (f32x4){0.f,0.f,0.f,0.f}; acv[mt] = (f32x4){0.f,0.f,0.f,0.f}; }
#pragma unroll
    for (int ks = 0; ks < 2; ++ks) {
        half8 bk = frag_f32(&Wk[(size_t)(g*64 + w*16 + l15)*64 + ks*32 + quad*8]);
        half8 bv = frag_f32(&Wv[(size_t)(g*64 + w*16 + l15)*64 + ks*32 + quad*8]);
#pragma unroll
        for (int mt = 0; mt < 2; ++mt) {
            ack[mt] = __builtin_amdgcn_mfma_f32_16x16x32_f16(af[mt][ks], bk, ack[mt], 0, 0, 0);
            acv[mt] = __builtin_amdgcn_mfma_f32_16x16x32_f16(af[mt][ks], bv, acv[mt], 0, 0, 0);
        }
    }
    // store: lane holds j = mt*16+quad*4+r, oc = w*16+l15
    size_t hb = (size_t)(s*8 + g);
#pragma unroll
    for (int mt = 0; mt < 2; ++mt) {
#pragma unroll
        for (int r = 0; r < 4; ++r)
            kt16[(hb*m + j0 + mt*16 + quad*4 + r)*64 + w*16 + l15] = (_Float16)ack[mt][r];
        union { fp16x2 h2[2]; uint2 v; } pv;
        pv.h2[0] = __builtin_amdgcn_cvt_pkrtz(acv[mt][0], acv[mt][1]);
        pv.h2[1] = __builtin_amdgcn_cvt_pkrtz(acv[mt][2], acv[mt][3]);
        *(uint2*)&vt16[(hb*64 + w*16 + l15)*m + j0 + mt*16 + quad*4] = pv.v;   // 4 consecutive j
    }
}

// ---------------- flash attention v5: K frags direct from global; V LDS-dbuf; vectored P^T ----------------
__global__ __launch_bounds__(256, 2) void k_attn(
    const _Float16* __restrict__ qh, const _Float16* __restrict__ kt16,
    const _Float16* __restrict__ vt16, _Float16* __restrict__ aoh, int n, int m)
{
    __shared__ _Float16 Vs[2][64*72];
    __shared__ _Float16 Ps[128*72];   // P^T strips; reused as O transpose buffer in epilogue
    int nit = n >> 7;
    int it = blockIdx.x % nit;
    int h  = (blockIdx.x / nit) & 7;
    int s  = blockIdx.x / (nit*8);
    int t  = threadIdx.x;
    int lane = t & 63, w = t >> 6;
    int l15 = lane & 15, quad = lane >> 4;
    int i0 = it*128;

    // Q B-frags: load once from global, keep in registers
    const _Float16* qb = &qh[((size_t)h*n + i0)*64];
    half8 bqv[2][2];
#pragma unroll
    for (int ks = 0; ks < 2; ++ks)
#pragma unroll
        for (int i2 = 0; i2 < 2; ++i2)
            bqv[ks][i2] = *(const half8*)&qb[(w*32 + i2*16 + l15)*64 + ks*32 + quad*8];

    const _Float16* kb = &kt16[(size_t)(s*8+h)*m*64];   // [j][d]
    const _Float16* vb = &vt16[(size_t)(s*8+h)*64*m];   // [d][j]

    int r0 = t >> 3, oct = t & 7;

    float lsum[2] = {0.f, 0.f};
    f32x4 oaccT[4][2];
#pragma unroll
    for (int dt = 0; dt < 4; ++dt)
#pragma unroll
        for (int i2 = 0; i2 < 2; ++i2) oaccT[dt][i2] = (f32x4){0.f,0.f,0.f,0.f};

    // prefetch + commit V tile 0 into buf 0
    uint4 pv0 = *(const uint4*)&vb[(size_t)r0*m + oct*8];
    uint4 pv1 = *(const uint4*)&vb[(size_t)(r0+32)*m + oct*8];
    *(uint4*)&Vs[0][r0*72 + oct*8]      = pv0;
    *(uint4*)&Vs[0][(r0+32)*72 + oct*8] = pv1;

    int ntile = m >> 6;
    for (int tk = 0; tk < ntile; ++tk) {
        bool pf = (tk + 1 < ntile);
        if (pf) {   // next V tile's global loads, latency hidden by compute
            pv0 = *(const uint4*)&vb[(size_t)r0*m + (tk+1)*64 + oct*8];
            pv1 = *(const uint4*)&vb[(size_t)(r0+32)*m + (tk+1)*64 + oct*8];
        }
        // K frags for this tile: direct global (L1-resident 8 KB tile)
        half8 aqv[2][4];
#pragma unroll
        for (int ks = 0; ks < 2; ++ks)
#pragma unroll
            for (int jt = 0; jt < 4; ++jt)
                aqv[ks][jt] = *(const half8*)&kb[(size_t)(tk*64 + jt*16 + l15)*64 + ks*32 + quad*8];

        __syncthreads();   // V buf[tk&1] committed; prior tile's reads done
        const _Float16* VB = Vs[tk & 1];
        half8 avv[2][4];
#pragma unroll
        for (int ks = 0; ks < 2; ++ks)
#pragma unroll
            for (int dt = 0; dt < 4; ++dt)
                avv[ks][dt] = *(const half8*)&VB[(dt*16 + l15)*72 + ks*32 + quad*8];

        // --- S^T = K Q^T over wave's 32-i strip ---
        f32x4 accs[4][2];
#pragma unroll
        for (int jt = 0; jt < 4; ++jt)
#pragma unroll
            for (int i2 = 0; i2 < 2; ++i2) accs[jt][i2] = (f32x4){0.f,0.f,0.f,0.f};
#pragma unroll
        for (int ks = 0; ks < 2; ++ks)
#pragma unroll
            for (int jt = 0; jt < 4; ++jt)
#pragma unroll
                for (int i2 = 0; i2 < 2; ++i2)
                    accs[jt][i2] = __builtin_amdgcn_mfma_f32_16x16x32_f16(
                        aqv[ks][jt], bqv[ks][i2], accs[jt][i2], 0, 0, 0);

        // --- p = exp2(t - MSHIFT); partial row sums; pack + vectored P^T write (wave-private) ---
#pragma unroll
        for (int jt = 0; jt < 4; ++jt)
#pragma unroll
            for (int i2 = 0; i2 < 2; ++i2) {
                f32x4 p;
#pragma unroll
                for (int r = 0; r < 4; ++r) p[r] = __builtin_amdgcn_exp2f(accs[jt][i2][r] - MSHIFT);
                lsum[i2] += (p[0]+p[1]) + (p[2]+p[3]);
                union { fp16x2 h; int i; } c0, c1;
                c0.h = __builtin_amdgcn_cvt_pkrtz(p[0], p[1]);
                c1.h = __builtin_amdgcn_cvt_pkrtz(p[2], p[3]);
                *(int2*)&Ps[(w*32 + i2*16 + l15)*72 + jt*16 + quad*4] = make_int2(c0.i, c1.i);
            }

        // --- O^T += V^T P^T ---
#pragma unroll
        for (int ks = 0; ks < 2; ++ks)
#pragma unroll
            for (int i2 = 0; i2 < 2; ++i2) {
                half8 bp = *(const half8*)&Ps[(w*32 + i2*16 + l15)*72 + ks*32 + quad*8];
#pragma unroll
                for (int dt = 0; dt < 4; ++dt)
                    oaccT[dt][i2] = __builtin_amdgcn_mfma_f32_16x16x32_f16(
                        avv[ks][dt], bp, oaccT[dt][i2], 0, 0, 0);
            }

        if (pf) {   // commit next V tile into the other buffer
            int b2 = (tk + 1) & 1;
            *(uint4*)&Vs[b2][r0*72 + oct*8]      = pv0;
            *(uint4*)&Vs[b2][(r0+32)*72 + oct*8] = pv1;
        }
    }

    // --- finalize ---
#pragma unroll
    for (int i2 = 0; i2 < 2; ++i2) {
        lsum[i2] += __shfl_xor(lsum[i2], 16, 64);
        lsum[i2] += __shfl_xor(lsum[i2], 32, 64);
    }
    float inv[2] = {1.0f / lsum[0], 1.0f / lsum[1]};
#pragma unroll
    for (int dt = 0; dt < 4; ++dt)
#pragma unroll
        for (int i2 = 0; i2 < 2; ++i2)
#pragma unroll
            for (int r = 0; r < 4; ++r)
                Ps[(w*32 + i2*16 + l15)*72 + dt*16 + quad*4 + r]
                    = (_Float16)(oaccT[dt][i2][r] * inv[i2]);
    {
        int row = w*32 + (lane >> 1);
        int dbase = (lane & 1) * 32;
        size_t gbase = (size_t)(i0 + row)*1024 + s*512 + h*64 + dbase;
#pragma unroll
        for (int k2 = 0; k2 < 4; ++k2) {
            uint4 v = *(uint4*)&Ps[row*72 + dbase + k2*8];
            *(uint4*)&aoh[gbase + k2*8] = v;
        }
    }
}

// ---------------- Wo GEMM, f16 MFMA, zero-LDS (A/B frags direct from global) ----------------
__global__ __launch_bounds__(256) void k_out(
    const _Float16* __restrict__ aoh, const _Float16* __restrict__ Woh,
    const float* __restrict__ bo, float* __restrict__ out, int n)
{
    int i0 = blockIdx.x*64, d0 = blockIdx.y*64;
    int t = threadIdx.x;
    int lane = t & 63, w = t >> 6;
    int l15 = lane & 15, quad = lane >> 4;
    f32x4 oacc[4];
#pragma unroll
    for (int dt = 0; dt < 4; ++dt) oacc[dt] = (f32x4){0.f,0.f,0.f,0.f};

    const _Float16* arow = &aoh[(size_t)(i0 + w*16 + l15)*1024 + quad*8];
#pragma unroll 4
    for (int ks = 0; ks < 32; ++ks) {            // K' = 1024
        half8 aq = *(const half8*)&arow[ks*32];
        int cbase = (ks & 15) * 32;              // c = c' & 511
#pragma unroll
        for (int dt = 0; dt < 4; ++dt) {
            half8 bw = *(const half8*)&Woh[(size_t)(d0 + dt*16 + l15)*DIMC + cbase + quad*8];
            oacc[dt] = __builtin_amdgcn_mfma_f32_16x16x32_f16(aq, bw, oacc[dt], 0, 0, 0);
        }
    }
#pragma unroll
    for (int dt = 0; dt < 4; ++dt) {
        float bias = bo[d0 + dt*16 + l15];
#pragma unroll
        for (int r = 0; r < 4; ++r)
            out[(size_t)(i0 + w*16 + quad*4 + r)*DIMC + d0 + dt*16 + l15]
                = bias + 0.5f*oacc[dt][r];
    }
}

extern "C" void kernel_launch(void* const* d_in, const int* in_sizes, int n_in,
                              void* d_out, int out_size, void* d_ws, size_t ws_size,
                              hipStream_t stream)
{
    const float* x   = (const float*)d_in[0];
    const float* px  = (const float*)d_in[1];
    const float* Wq  = (const float*)d_in[2];
    const float* Wk  = (const float*)d_in[3];
    const float* Wv  = (const float*)d_in[4];
    const float* Wo  = (const float*)d_in[5];
    const float* bo  = (const float*)d_in[6];
    const float* Wdw = (const float*)d_in[7];
    const float* bdw = (const float*)d_in[8];
    const float* Wp  = (const float*)d_in[9];
    float* out = (float*)d_out;
    int n = in_sizes[0] / DIMC;     // 4096
    int m = n / 4;                  // 1024

    float* ws  = (float*)d_ws;
    int*   x0i  = (int*)ws;                           // 8*m
    float* w1f  = (float*)(x0i + 8*m);                // 8*m
    _Float16* qhf  = (_Float16*)(w1f + 8*m);          // 8*n*64 f16   [h][i][d]
    _Float16* kt16 = qhf + (size_t)8*n*64;            // 2*8*m*64 f16 [s][h][j][d]
    _Float16* vt16 = kt16 + (size_t)16*m*64;          // 2*8*m*64 f16 [s][h][d][j]
    _Float16* aoh  = vt16 + (size_t)16*m*64;          // n*1024 f16   [i][c']
    _Float16* Woh  = aoh + (size_t)n*1024;            // 512*512 f16  [d][c]

    k_qoff <<<8*(m/32),         256, 0, stream>>>(x, px, Wq, Wdw, bdw, Wp, qhf, x0i, w1f, n, m);
    k_kv   <<<2*8*(m/32),       256, 0, stream>>>(x, px, Wk, Wv, Wo, x0i, w1f, kt16, vt16, Woh, n, m);
    k_attn <<<2*8*(n/128),      256, 0, stream>>>(qhf, kt16, vt16, aoh, n, m);
    k_out  <<<dim3(n/64, 8),    256, 0, stream>>>(aoh, Woh, bo, out, n);
}

// Round 11
// 168.904 us; speedup vs baseline: 1.3766x; 1.0291x over previous
//
#include <hip/hip_runtime.h>
#include <math.h>

#define DIMC 512
#define NG 8
// q pre-scale: 64^-0.5 * log2(e)  (so scores come out in exp2 units)
#define QSCALE 0.18033688011112042f
// softmax fixed shift: 5 * log2(e)
#define MSHIFT 7.2134752044448170f

typedef _Float16 half8 __attribute__((ext_vector_type(8)));
typedef __fp16 fp16x2 __attribute__((ext_vector_type(2)));
typedef float f32x4 __attribute__((ext_vector_type(4)));

// build a half8 MFMA fragment from 8 consecutive global f32
__device__ __forceinline__ half8 frag_f32(const float* p) {
    float4 a = *(const float4*)p;
    float4 b = *(const float4*)(p + 4);
    union { fp16x2 h2[4]; half8 h8; } u;
    u.h2[0] = __builtin_amdgcn_cvt_pkrtz(a.x, a.y);
    u.h2[1] = __builtin_amdgcn_cvt_pkrtz(a.z, a.w);
    u.h2[2] = __builtin_amdgcn_cvt_pkrtz(b.x, b.y);
    u.h2[3] = __builtin_amdgcn_cvt_pkrtz(b.z, b.w);
    return u.h8;
}

// ---------------- fused front-end: q conv + qh + offset net + grid-sample + k/v convs ----------------
// Block = (g, 128-position q-tile == 32 m-positions). Offsets live only in LDS.
// Also: first 128 blocks cast Wo f32->f16 (consumed 2 dispatches later by k_out).
__global__ __launch_bounds__(256) void k_front(
    const float* __restrict__ x, const float* __restrict__ px,
    const float* __restrict__ Wq, const float* __restrict__ Wk,
    const float* __restrict__ Wv, const float* __restrict__ Wo,
    const float* __restrict__ Wdw, const float* __restrict__ bdw,
    const float* __restrict__ Wp, _Float16* __restrict__ qh,
    _Float16* __restrict__ kt16, _Float16* __restrict__ vt16,
    _Float16* __restrict__ Woh, int n, int m)
{
    __shared__ float Os[128*69];      // [i][oc] q tile, stride 69
    __shared__ float hl[2][64];       // halo q: [side][c]
    __shared__ float part[8][36];
    __shared__ int   x0s[32];
    __shared__ float w1s[32];
    __shared__ _Float16 kvs[2][32*72]; // gathered kv, per stream
    int g  = blockIdx.x & 7;
    int jt = blockIdx.x >> 3;
    int P0 = jt*128, j0 = jt*32;
    int t  = threadIdx.x;
    int lane = t & 63, w = t >> 6;
    int l15 = lane & 15, quad = lane >> 4;
    const float* SRC = (g < 4) ? px : x;    // concat puts prev first
    int cbase = (g & 3) * 128;

    // Wo cast (first 128 blocks, 2048 elems each); k_out runs 2 dispatches later
    if (blockIdx.x < 128) {
        int idx = blockIdx.x*2048 + t*8;
        float4 a = *(const float4*)&Wo[idx];
        float4 b = *(const float4*)&Wo[idx+4];
        union { fp16x2 h2[4]; uint4 v; } pk;
        pk.h2[0] = __builtin_amdgcn_cvt_pkrtz(a.x, a.y);
        pk.h2[1] = __builtin_amdgcn_cvt_pkrtz(a.z, a.w);
        pk.h2[2] = __builtin_amdgcn_cvt_pkrtz(b.x, b.y);
        pk.h2[3] = __builtin_amdgcn_cvt_pkrtz(b.z, b.w);
        *(uint4*)&Woh[idx] = pk.v;
    }

    // halo q (fp32 exact, zero-padded at edges), 128 threads
    if (t < 128) {
        int side = t >> 6, c = t & 63;
        int p = P0 + (side ? 128 : -1);
        float hsum = 0.f;
        if (p >= 0 && p < n) {
            const float* xr = &SRC[(size_t)p*DIMC + cbase];
            const float* wr = &Wq[(size_t)(g*64 + c)*128];
#pragma unroll 8
            for (int k = 0; k < 32; ++k) {
                float4 xv = *(const float4*)&xr[k*4];
                float4 wv = *(const float4*)&wr[k*4];
                hsum += xv.x*wv.x + xv.y*wv.y + xv.z*wv.z + xv.w*wv.w;
            }
        }
        hl[side][c] = hsum;
    }

    // main q tile via f16 MFMA: wave w owns i-strip [P0+w*32, +32)
    half8 af[2][4];
#pragma unroll
    for (int mt = 0; mt < 2; ++mt)
#pragma unroll
        for (int ks = 0; ks < 4; ++ks)
            af[mt][ks] = frag_f32(&SRC[(size_t)(P0 + w*32 + mt*16 + l15)*DIMC + cbase + ks*32 + quad*8]);
    f32x4 acc[2][4];
#pragma unroll
    for (int mt = 0; mt < 2; ++mt)
#pragma unroll
        for (int nt = 0; nt < 4; ++nt) acc[mt][nt] = (f32x4){0.f,0.f,0.f,0.f};
#pragma unroll
    for (int ks = 0; ks < 4; ++ks)
#pragma unroll
        for (int nt = 0; nt < 4; ++nt) {
            half8 bf = frag_f32(&Wq[(size_t)(g*64 + nt*16 + l15)*128 + ks*32 + quad*8]);
#pragma unroll
            for (int mt = 0; mt < 2; ++mt)
                acc[mt][nt] = __builtin_amdgcn_mfma_f32_16x16x32_f16(af[mt][ks], bf, acc[mt][nt], 0, 0, 0);
        }
    // C-layout -> Os[i][oc]
#pragma unroll
    for (int mt = 0; mt < 2; ++mt)
#pragma unroll
        for (int nt = 0; nt < 4; ++nt)
#pragma unroll
            for (int r = 0; r < 4; ++r)
                Os[(w*32 + mt*16 + quad*4 + r)*69 + nt*16 + l15] = acc[mt][nt][r];
    __syncthreads();

    // qh f16 [h][i][d] with QSCALE: thread covers half a row (32 f16)
    {
        int i = t >> 1, hf = t & 1;
        union { _Float16 h[32]; uint4 v[4]; } pk;
#pragma unroll
        for (int u = 0; u < 32; ++u) pk.h[u] = (_Float16)(Os[i*69 + hf*32 + u] * QSCALE);
        uint4* dst = (uint4*)&qh[((size_t)g*n + P0 + i)*64 + hf*32];
        dst[0] = pk.v[0]; dst[1] = pk.v[1]; dst[2] = pk.v[2]; dst[3] = pk.v[3];
    }

    // offset net straight from LDS: thread = (j = t&31, cg = t>>5)
    {
        int j = t & 31, cg = t >> 5;
        float acco = 0.f;
#pragma unroll
        for (int cc = 0; cc < 8; ++cc) {
            int c = cg*8 + cc;
            float h = bdw[c];
#pragma unroll
            for (int tt = 0; tt < 6; ++tt) {
                int lp = 4*j + tt - 1;
                float val = (lp < 0) ? hl[0][c] : (lp >= 128 ? hl[1][c] : Os[lp*69 + c]);
                h += Wdw[c*6 + tt] * val;
            }
            float ge = 0.5f * h * (1.0f + erff(h * 0.70710678118654752f));  // exact gelu
            acco += Wp[c] * ge;
        }
        part[cg][j] = acco;
    }
    __syncthreads();
    if (t < 32) {
        float off = 0.f;
#pragma unroll
        for (int cg2 = 0; cg2 < 8; ++cg2) off += part[cg2][t];
        off = tanhf(off) * 4.0f;
        int jg = j0 + t;
        float vg  = 2.0f * ((float)jg + off) / (float)(m - 1) - 1.0f;
        float pos = ((vg + 1.0f) * (float)n - 1.0f) * 0.5f;
        float x0  = floorf(pos);
        x0s[t] = (int)x0;
        w1s[t] = pos - x0;
    }
    __syncthreads();

    // grid-sample gather, both streams (prefetch loads, then lerp+commit)
    {
        float a0[8], a1[8], b0[8], b1[8], wg[8];
#pragma unroll
        for (int jj = 0; jj < 8; ++jj) {
            int j = jj*4 + w;
            int ii = x0s[j];
            wg[jj] = w1s[j];
            bool v0 = (ii   >= 0 && ii   < n);
            bool v1 = (ii+1 >= 0 && ii+1 < n);
            a0[jj] = v0 ? px[(size_t)ii*DIMC + g*64 + lane]     : 0.f;
            a1[jj] = v1 ? px[(size_t)(ii+1)*DIMC + g*64 + lane] : 0.f;
            b0[jj] = v0 ? x[(size_t)ii*DIMC + g*64 + lane]      : 0.f;
            b1[jj] = v1 ? x[(size_t)(ii+1)*DIMC + g*64 + lane]  : 0.f;
        }
#pragma unroll
        for (int jj = 0; jj < 8; ++jj) {
            kvs[0][(jj*4 + w)*72 + lane] = (_Float16)(a0[jj]*(1.0f - wg[jj]) + a1[jj]*wg[jj]);
            kvs[1][(jj*4 + w)*72 + lane] = (_Float16)(b0[jj]*(1.0f - wg[jj]) + b1[jj]*wg[jj]);
        }
    }
    __syncthreads();

    // k/v convs: B-frags from global (shared across streams); wave w owns oc-strip w*16
    half8 bk[2], bv[2];
#pragma unroll
    for (int ks = 0; ks < 2; ++ks) {
        bk[ks] = frag_f32(&Wk[(size_t)(g*64 + w*16 + l15)*64 + ks*32 + quad*8]);
        bv[ks] = frag_f32(&Wv[(size_t)(g*64 + w*16 + l15)*64 + ks*32 + quad*8]);
    }
#pragma unroll
    for (int s = 0; s < 2; ++s) {
        half8 afk[2][2];   // [mt][ks]
#pragma unroll
        for (int mt = 0; mt < 2; ++mt)
#pragma unroll
            for (int ks = 0; ks < 2; ++ks)
                afk[mt][ks] = *(const half8*)&kvs[s][(mt*16 + l15)*72 + ks*32 + quad*8];
        f32x4 ack[2], acv[2];
#pragma unroll
        for (int mt = 0; mt < 2; ++mt) { ack[mt] = (f32x4){0.f,0.f,0.f,0.f}; acv[mt] = (f32x4){0.f,0.f,0.f,0.f}; }
#pragma unroll
        for (int ks = 0; ks < 2; ++ks)
#pragma unroll
            for (int mt = 0; mt < 2; ++mt) {
                ack[mt] = __builtin_amdgcn_mfma_f32_16x16x32_f16(afk[mt][ks], bk[ks], ack[mt], 0, 0, 0);
                acv[mt] = __builtin_amdgcn_mfma_f32_16x16x32_f16(afk[mt][ks], bv[ks], acv[mt], 0, 0, 0);
            }
        size_t hb = (size_t)(s*8 + g);
#pragma unroll
        for (int mt = 0; mt < 2; ++mt) {
#pragma unroll
            for (int r = 0; r < 4; ++r)
                kt16[(hb*m + j0 + mt*16 + quad*4 + r)*64 + w*16 + l15] = (_Float16)ack[mt][r];
            union { fp16x2 h2[2]; uint2 v; } pv;
            pv.h2[0] = __builtin_amdgcn_cvt_pkrtz(acv[mt][0], acv[mt][1]);
            pv.h2[1] = __builtin_amdgcn_cvt_pkrtz(acv[mt][2], acv[mt][3]);
            *(uint2*)&vt16[(hb*64 + w*16 + l15)*m + j0 + mt*16 + quad*4] = pv.v;   // 4 consecutive j
        }
    }
}

// ---------------- flash attention v5: K frags direct from global; V LDS-dbuf; vectored P^T ----------------
__global__ __launch_bounds__(256, 2) void k_attn(
    const _Float16* __restrict__ qh, const _Float16* __restrict__ kt16,
    const _Float16* __restrict__ vt16, _Float16* __restrict__ aoh, int n, int m)
{
    __shared__ _Float16 Vs[2][64*72];
    __shared__ _Float16 Ps[128*72];   // P^T strips; reused as O transpose buffer in epilogue
    int nit = n >> 7;
    int it = blockIdx.x % nit;
    int h  = (blockIdx.x / nit) & 7;
    int s  = blockIdx.x / (nit*8);
    int t  = threadIdx.x;
    int lane = t & 63, w = t >> 6;
    int l15 = lane & 15, quad = lane >> 4;
    int i0 = it*128;

    // Q B-frags: load once from global, keep in registers
    const _Float16* qb = &qh[((size_t)h*n + i0)*64];
    half8 bqv[2][2];
#pragma unroll
    for (int ks = 0; ks < 2; ++ks)
#pragma unroll
        for (int i2 = 0; i2 < 2; ++i2)
            bqv[ks][i2] = *(const half8*)&qb[(w*32 + i2*16 + l15)*64 + ks*32 + quad*8];

    const _Float16* kb = &kt16[(size_t)(s*8+h)*m*64];   // [j][d]
    const _Float16* vb = &vt16[(size_t)(s*8+h)*64*m];   // [d][j]

    int r0 = t >> 3, oct = t & 7;

    float lsum[2] = {0.f, 0.f};
    f32x4 oaccT[4][2];
#pragma unroll
    for (int dt = 0; dt < 4; ++dt)
#pragma unroll
        for (int i2 = 0; i2 < 2; ++i2) oaccT[dt][i2] = (f32x4){0.f,0.f,0.f,0.f};

    // prefetch + commit V tile 0 into buf 0
    uint4 pv0 = *(const uint4*)&vb[(size_t)r0*m + oct*8];
    uint4 pv1 = *(const uint4*)&vb[(size_t)(r0+32)*m + oct*8];
    *(uint4*)&Vs[0][r0*72 + oct*8]      = pv0;
    *(uint4*)&Vs[0][(r0+32)*72 + oct*8] = pv1;

    int ntile = m >> 6;
    for (int tk = 0; tk < ntile; ++tk) {
        bool pf = (tk + 1 < ntile);
        if (pf) {   // next V tile's global loads, latency hidden by compute
            pv0 = *(const uint4*)&vb[(size_t)r0*m + (tk+1)*64 + oct*8];
            pv1 = *(const uint4*)&vb[(size_t)(r0+32)*m + (tk+1)*64 + oct*8];
        }
        // K frags for this tile: direct global (L1-resident 8 KB tile)
        half8 aqv[2][4];
#pragma unroll
        for (int ks = 0; ks < 2; ++ks)
#pragma unroll
            for (int jt = 0; jt < 4; ++jt)
                aqv[ks][jt] = *(const half8*)&kb[(size_t)(tk*64 + jt*16 + l15)*64 + ks*32 + quad*8];

        __syncthreads();   // V buf[tk&1] committed; prior tile's reads done
        const _Float16* VB = Vs[tk & 1];
        half8 avv[2][4];
#pragma unroll
        for (int ks = 0; ks < 2; ++ks)
#pragma unroll
            for (int dt = 0; dt < 4; ++dt)
                avv[ks][dt] = *(const half8*)&VB[(dt*16 + l15)*72 + ks*32 + quad*8];

        // --- S^T = K Q^T over wave's 32-i strip ---
        f32x4 accs[4][2];
#pragma unroll
        for (int jt = 0; jt < 4; ++jt)
#pragma unroll
            for (int i2 = 0; i2 < 2; ++i2) accs[jt][i2] = (f32x4){0.f,0.f,0.f,0.f};
#pragma unroll
        for (int ks = 0; ks < 2; ++ks)
#pragma unroll
            for (int jt = 0; jt < 4; ++jt)
#pragma unroll
                for (int i2 = 0; i2 < 2; ++i2)
                    accs[jt][i2] = __builtin_amdgcn_mfma_f32_16x16x32_f16(
                        aqv[ks][jt], bqv[ks][i2], accs[jt][i2], 0, 0, 0);

        // --- p = exp2(t - MSHIFT); partial row sums; pack + vectored P^T write (wave-private) ---
#pragma unroll
        for (int jt = 0; jt < 4; ++jt)
#pragma unroll
            for (int i2 = 0; i2 < 2; ++i2) {
                f32x4 p;
#pragma unroll
                for (int r = 0; r < 4; ++r) p[r] = __builtin_amdgcn_exp2f(accs[jt][i2][r] - MSHIFT);
                lsum[i2] += (p[0]+p[1]) + (p[2]+p[3]);
                union { fp16x2 h; int i; } c0, c1;
                c0.h = __builtin_amdgcn_cvt_pkrtz(p[0], p[1]);
                c1.h = __builtin_amdgcn_cvt_pkrtz(p[2], p[3]);
                *(int2*)&Ps[(w*32 + i2*16 + l15)*72 + jt*16 + quad*4] = make_int2(c0.i, c1.i);
            }

        // --- O^T += V^T P^T ---
#pragma unroll
        for (int ks = 0; ks < 2; ++ks)
#pragma unroll
            for (int i2 = 0; i2 < 2; ++i2) {
                half8 bp = *(const half8*)&Ps[(w*32 + i2*16 + l15)*72 + ks*32 + quad*8];
#pragma unroll
                for (int dt = 0; dt < 4; ++dt)
                    oaccT[dt][i2] = __builtin_amdgcn_mfma_f32_16x16x32_f16(
                        avv[ks][dt], bp, oaccT[dt][i2], 0, 0, 0);
            }

        if (pf) {   // commit next V tile into the other buffer
            int b2 = (tk + 1) & 1;
            *(uint4*)&Vs[b2][r0*72 + oct*8]      = pv0;
            *(uint4*)&Vs[b2][(r0+32)*72 + oct*8] = pv1;
        }
    }

    // --- finalize ---
#pragma unroll
    for (int i2 = 0; i2 < 2; ++i2) {
        lsum[i2] += __shfl_xor(lsum[i2], 16, 64);
        lsum[i2] += __shfl_xor(lsum[i2], 32, 64);
    }
    float inv[2] = {1.0f / lsum[0], 1.0f / lsum[1]};
#pragma unroll
    for (int dt = 0; dt < 4; ++dt)
#pragma unroll
        for (int i2 = 0; i2 < 2; ++i2)
#pragma unroll
            for (int r = 0; r < 4; ++r)
                Ps[(w*32 + i2*16 + l15)*72 + dt*16 + quad*4 + r]
                    = (_Float16)(oaccT[dt][i2][r] * inv[i2]);
    {
        int row = w*32 + (lane >> 1);
        int dbase = (lane & 1) * 32;
        size_t gbase = (size_t)(i0 + row)*1024 + s*512 + h*64 + dbase;
#pragma unroll
        for (int k2 = 0; k2 < 4; ++k2) {
            uint4 v = *(uint4*)&Ps[row*72 + dbase + k2*8];
            *(uint4*)&aoh[gbase + k2*8] = v;
        }
    }
}

// ---------------- Wo GEMM, f16 MFMA, zero-LDS (A/B frags direct from global) ----------------
__global__ __launch_bounds__(256) void k_out(
    const _Float16* __restrict__ aoh, const _Float16* __restrict__ Woh,
    const float* __restrict__ bo, float* __restrict__ out, int n)
{
    int i0 = blockIdx.x*64, d0 = blockIdx.y*64;
    int t = threadIdx.x;
    int lane = t & 63, w = t >> 6;
    int l15 = lane & 15, quad = lane >> 4;
    f32x4 oacc[4];
#pragma unroll
    for (int dt = 0; dt < 4; ++dt) oacc[dt] = (f32x4){0.f,0.f,0.f,0.f};

    const _Float16* arow = &aoh[(size_t)(i0 + w*16 + l15)*1024 + quad*8];
#pragma unroll 4
    for (int ks = 0; ks < 32; ++ks) {            // K' = 1024
        half8 aq = *(const half8*)&arow[ks*32];
        int cbase = (ks & 15) * 32;              // c = c' & 511
#pragma unroll
        for (int dt = 0; dt < 4; ++dt) {
            half8 bw = *(const half8*)&Woh[(size_t)(d0 + dt*16 + l15)*DIMC + cbase + quad*8];
            oacc[dt] = __builtin_amdgcn_mfma_f32_16x16x32_f16(aq, bw, oacc[dt], 0, 0, 0);
        }
    }
#pragma unroll
    for (int dt = 0; dt < 4; ++dt) {
        float bias = bo[d0 + dt*16 + l15];
#pragma unroll
        for (int r = 0; r < 4; ++r)
            out[(size_t)(i0 + w*16 + quad*4 + r)*DIMC + d0 + dt*16 + l15]
                = bias + 0.5f*oacc[dt][r];
    }
}

extern "C" void kernel_launch(void* const* d_in, const int* in_sizes, int n_in,
                              void* d_out, int out_size, void* d_ws, size_t ws_size,
                              hipStream_t stream)
{
    const float* x   = (const float*)d_in[0];
    const float* px  = (const float*)d_in[1];
    const float* Wq  = (const float*)d_in[2];
    const float* Wk  = (const float*)d_in[3];
    const float* Wv  = (const float*)d_in[4];
    const float* Wo  = (const float*)d_in[5];
    const float* bo  = (const float*)d_in[6];
    const float* Wdw = (const float*)d_in[7];
    const float* bdw = (const float*)d_in[8];
    const float* Wp  = (const float*)d_in[9];
    float* out = (float*)d_out;
    int n = in_sizes[0] / DIMC;     // 4096
    int m = n / 4;                  // 1024

    _Float16* qhf  = (_Float16*)d_ws;                 // 8*n*64 f16   [h][i][d]
    _Float16* kt16 = qhf + (size_t)8*n*64;            // 2*8*m*64 f16 [s][h][j][d]
    _Float16* vt16 = kt16 + (size_t)16*m*64;          // 2*8*m*64 f16 [s][h][d][j]
    _Float16* aoh  = vt16 + (size_t)16*m*64;          // n*1024 f16   [i][c']
    _Float16* Woh  = aoh + (size_t)n*1024;            // 512*512 f16  [d][c]

    k_front<<<8*(m/32),    256, 0, stream>>>(x, px, Wq, Wk, Wv, Wo, Wdw, bdw, Wp,
                                             qhf, kt16, vt16, Woh, n, m);
    k_attn <<<2*8*(n/128), 256, 0, stream>>>(qhf, kt16, vt16, aoh, n, m);
    k_out  <<<dim3(n/64, 8), 256, 0, stream>>>(aoh, Woh, bo, out, n);
}